// Round 7
// baseline (5648.468 us; speedup 1.0000x reference)
//
#include <hip/hip_runtime.h>
#include <stdint.h>

#define NTOK 10992      // B*SN
#define NTOKA 11264     // padded token dim
#define PMi 4194304

typedef unsigned short u16;
typedef __attribute__((ext_vector_type(8))) __bf16 b8;
typedef __attribute__((ext_vector_type(4))) float f32x4;

__device__ __forceinline__ u16 f2b(float f) {
  union { float f; uint32_t u; } v; v.f = f;
  return (u16)((v.u + 0x7fffu + ((v.u >> 16) & 1u)) >> 16);   // RNE
}
__device__ __forceinline__ float b2f(u16 b) {
  union { uint32_t u; float f; } v; v.u = ((uint32_t)b) << 16; return v.f;
}
__device__ __forceinline__ uint2 pk4(u16 a, u16 b, u16 c, u16 d) {
  uint2 r; r.x = (uint32_t)a | ((uint32_t)b << 16); r.y = (uint32_t)c | ((uint32_t)d << 16);
  return r;
}
__device__ __forceinline__ void gload16(const u16* g, u16* l) {
  __builtin_amdgcn_global_load_lds((const __attribute__((address_space(1))) void*)(const void*)g,
                                   (__attribute__((address_space(3))) void*)(void*)l, 16, 0, 0);
}

struct GA {
  const u16* A[3]; const u16* B[3];
  void* C[3]; u16* O1[3]; u16* OT[3];
  const void* E0[3]; const u16* E1[3];
  int lda[3], ldb[3];
  int M, N, K, ldc, ldo1, ldt, lde0, lde1;
  float p0, p1;
};

struct SP {
  const float *gg, *gv, *gp, *pw;
  u16 *Gt, *Vt, *Pt, *projWt, *Pb;
};

// ---------------- 128x128 tile GEMM: C[m,n] = sum_k A[m,k]*B[n,k] ----------------
// EPI: 0 Cb=acc | 5 dzg=acc*E0b->C(T-pack), dzv=acc*E1b->O1(T-pack)
//      6 Cf=acc+E0f[n] | 8 atomicAdd(Cf, acc)
//      16 Muon fused apply: Cb (X^T-layout) -= 0.1*acc via uint2 RMW; O1=Pt scatter
template <int EPI, int SPLIT>
__global__ __launch_bounds__(256, 2) void gemm_bt(GA g) {
  __shared__ u16 As[128 * 32];
  __shared__ u16 Bs[128 * 32];
  int bz = blockIdx.z, koff = 0, klen = g.K;
  if constexpr (SPLIT) { koff = (bz & 1) * (g.K >> 1); bz >>= 1; klen = g.K >> 1; }
  const u16* __restrict__ A = g.A[bz] + koff;
  const u16* __restrict__ B = g.B[bz] + koff;
  const int lda = g.lda[bz], ldb = g.ldb[bz];
  const int m0 = blockIdx.y * 128, n0 = blockIdx.x * 128;
  const int tid = threadIdx.x, w = tid >> 6, lane = tid & 63;
  const int wr = (w >> 1) * 64, wc = (w & 1) * 64;
  const int ln = lane & 15, lq = lane >> 4;

  f32x4 acc[4][4];
#pragma unroll
  for (int i = 0; i < 4; ++i)
#pragma unroll
    for (int j = 0; j < 4; ++j)
#pragma unroll
      for (int r = 0; r < 4; ++r) acc[i][j][r] = 0.f;

  const u16* Ag = A + (size_t)(m0 + 32 * w + (lane >> 2)) * lda + (lane & 3) * 8;
  const u16* Bg = B + (size_t)(n0 + 32 * w + (lane >> 2)) * ldb + (lane & 3) * 8;
  u16* AsW = &As[w * 1024];
  u16* BsW = &Bs[w * 1024];
  const int nkt = klen >> 5;

  for (int kt = 0; kt < nkt; ++kt) {
    __syncthreads();
    gload16(Ag, AsW);
    gload16(Ag + (size_t)16 * lda, AsW + 512);
    gload16(Bg, BsW);
    gload16(Bg + (size_t)16 * ldb, BsW + 512);
    Ag += 32; Bg += 32;
    __syncthreads();
    b8 af[4], bfr[4];
#pragma unroll
    for (int i = 0; i < 4; ++i) af[i] = *(const b8*)&As[(wr + i * 16 + ln) * 32 + lq * 8];
#pragma unroll
    for (int j = 0; j < 4; ++j) bfr[j] = *(const b8*)&Bs[(wc + j * 16 + ln) * 32 + lq * 8];
#pragma unroll
    for (int i = 0; i < 4; ++i)
#pragma unroll
      for (int j = 0; j < 4; ++j)
        acc[i][j] = __builtin_amdgcn_mfma_f32_16x16x32_bf16(af[i], bfr[j], acc[i][j], 0, 0, 0);
  }

  float* Cf = (float*)g.C[bz];
  u16* Cb = (u16*)g.C[bz];
  u16* O1 = g.O1[bz];
  const float* E0f = (const float*)g.E0[bz];
  const u16* E0b = (const u16*)g.E0[bz];
  const u16* E1b = g.E1[bz];

#pragma unroll
  for (int i = 0; i < 4; ++i) {
    const int mb = m0 + wr + i * 16 + lq * 4;
    if (mb >= g.M) continue;
#pragma unroll
    for (int j = 0; j < 4; ++j) {
      const int n = n0 + wc + j * 16 + ln;
      if (n >= g.N) continue;
      float vv[4];
#pragma unroll
      for (int r = 0; r < 4; ++r) vv[r] = acc[i][j][r];
      if constexpr (EPI == 0) {
#pragma unroll
        for (int r = 0; r < 4; ++r) Cb[(size_t)(mb + r) * g.ldc + n] = f2b(vv[r]);
      } else if constexpr (EPI == 5) {
        u16 cq[4], oq[4];
#pragma unroll
        for (int r = 0; r < 4; ++r) {
          const int m = mb + r;
          const float f1 = b2f(E0b[(size_t)m * g.lde0 + n]);
          const float f2 = b2f(E1b[(size_t)m * g.lde1 + n]);
          cq[r] = f2b(vv[r] * f1);
          oq[r] = f2b(vv[r] * f2);
        }
        *(uint2*)&Cb[(size_t)n * g.ldt + mb] = pk4(cq[0], cq[1], cq[2], cq[3]);
        *(uint2*)&O1[(size_t)n * g.ldt + mb] = pk4(oq[0], oq[1], oq[2], oq[3]);
      } else if constexpr (EPI == 6) {
        const float bias = E0f[n];
#pragma unroll
        for (int r = 0; r < 4; ++r) Cf[(size_t)(mb + r) * g.ldc + n] = vv[r] + bias;
      } else if constexpr (EPI == 8) {
#pragma unroll
        for (int r = 0; r < 4; ++r) atomicAdd(&Cf[(size_t)(mb + r) * g.ldc + n], vv[r]);
      } else if constexpr (EPI == 16) {
        uint2 old = *(const uint2*)&Cb[(size_t)n * 1024 + mb];
        u16 nq[4];
        nq[0] = f2b(b2f((u16)(old.x & 0xffff)) - 0.1f * vv[0]);
        nq[1] = f2b(b2f((u16)(old.x >> 16)) - 0.1f * vv[1]);
        nq[2] = f2b(b2f((u16)(old.y & 0xffff)) - 0.1f * vv[2]);
        nq[3] = f2b(b2f((u16)(old.y >> 16)) - 0.1f * vv[3]);
        *(uint2*)&Cb[(size_t)n * 1024 + mb] = pk4(nq[0], nq[1], nq[2], nq[3]);
        if (O1) {
#pragma unroll
          for (int r = 0; r < 4; ++r) O1[(size_t)(mb + r) * 4096 + n] = nq[r];
        }
      }
    }
  }
}

// ---------------- setup mega-fusion ----------------
// y < 86: qkv GEMM + head-L2-norm epilogue (writes qb, kb+kT, vT)
// y >= 86: flat id -> {Gt,Vt,Pt,projWt transposes; Pb cvt}
__global__ __launch_bounds__(256, 2) void setup_fused(GA g, SP s) {
  __shared__ u16 As[128 * 32];
  __shared__ u16 Bs[128 * 32];
  const int tid = threadIdx.x;

  if ((int)blockIdx.y >= 86) {
    const int id = ((int)blockIdx.y - 86) * 24 + (int)blockIdx.x;
    if (id >= 14336) return;
    if (id >= 13312) {  // Pb cvt: 1024 blocks x 4096 elems
      const int off = (id - 13312) * 4096;
#pragma unroll 4
      for (int i = tid; i < 4096; i += 256) s.Pb[off + i] = f2b(s.gp[off + i]);
      return;
    }
    const float* in; u16* outp; int Cin, Rtot, bx, by;
    if (id < 4096)       { in = s.gg; outp = s.Gt; Cin = 4096; Rtot = 1024; bx = id & 127; by = id >> 7; }
    else if (id < 8192)  { const int t2 = id - 4096; in = s.gv; outp = s.Vt; Cin = 4096; Rtot = 1024; bx = t2 & 127; by = t2 >> 7; }
    else if (id < 12288) { const int t2 = id - 8192; in = s.gp; outp = s.Pt; Cin = 1024; Rtot = 4096; bx = t2 & 31; by = t2 >> 5; }
    else                 { const int t2 = id - 12288; in = s.pw; outp = s.projWt; Cin = 1024; Rtot = 1024; bx = t2 & 31; by = t2 >> 5; }
    const int c0 = bx * 32, r0 = by * 32;
    const int tx = tid & 31, ty = tid >> 5;
    u16 (*tt)[33] = (u16(*)[33])As;
#pragma unroll
    for (int yy = 0; yy < 4; ++yy) {
      const int rr = ty * 4 + yy;
      tt[rr][tx] = f2b(in[(size_t)(r0 + rr) * Cin + c0 + tx]);
    }
    __syncthreads();
#pragma unroll
    for (int yy = 0; yy < 4; ++yy) {
      const int cc = ty * 4 + yy;
      outp[(size_t)(c0 + cc) * Rtot + r0 + tx] = tt[tx][cc];
    }
    return;
  }

  // ---- qkv + norm path ----
  const u16* __restrict__ A = g.A[0];
  const u16* __restrict__ B = g.B[0];
  const int lda = g.lda[0], ldb = g.ldb[0];
  const int m0 = blockIdx.y * 128, n0 = blockIdx.x * 128;
  const int w = tid >> 6, lane = tid & 63;
  const int wr = (w >> 1) * 64, wc = (w & 1) * 64;
  const int ln = lane & 15, lq = lane >> 4;

  f32x4 acc[4][4];
#pragma unroll
  for (int i = 0; i < 4; ++i)
#pragma unroll
    for (int j = 0; j < 4; ++j)
#pragma unroll
      for (int r = 0; r < 4; ++r) acc[i][j][r] = 0.f;

  const u16* Ag = A + (size_t)(m0 + 32 * w + (lane >> 2)) * lda + (lane & 3) * 8;
  const u16* Bg = B + (size_t)(n0 + 32 * w + (lane >> 2)) * ldb + (lane & 3) * 8;
  u16* AsW = &As[w * 1024];
  u16* BsW = &Bs[w * 1024];
  const int nkt = g.K >> 5;

  for (int kt = 0; kt < nkt; ++kt) {
    __syncthreads();
    gload16(Ag, AsW);
    gload16(Ag + (size_t)16 * lda, AsW + 512);
    gload16(Bg, BsW);
    gload16(Bg + (size_t)16 * ldb, BsW + 512);
    Ag += 32; Bg += 32;
    __syncthreads();
    b8 af[4], bfr[4];
#pragma unroll
    for (int i = 0; i < 4; ++i) af[i] = *(const b8*)&As[(wr + i * 16 + ln) * 32 + lq * 8];
#pragma unroll
    for (int j = 0; j < 4; ++j) bfr[j] = *(const b8*)&Bs[(wc + j * 16 + ln) * 32 + lq * 8];
#pragma unroll
    for (int i = 0; i < 4; ++i)
#pragma unroll
      for (int j = 0; j < 4; ++j)
        acc[i][j] = __builtin_amdgcn_mfma_f32_16x16x32_bf16(af[i], bfr[j], acc[i][j], 0, 0, 0);
  }

  u16* qbp = (u16*)g.C[0];
  u16* kbp = g.O1[0];
  u16* kTp = g.OT[0];
  u16* vTp = g.OT[1];
  const float* bias = (const float*)g.E0[0];
  const float* qS = (const float*)g.E0[1];
  const float* kS = (const float*)g.E0[2];
  const float* qB = (const float*)g.E1[0];
  const float* kB = (const float*)g.E1[1];
  const int seg = (n0 + wc) >> 10;   // 0=q, 1=k, 2=v

#pragma unroll
  for (int i = 0; i < 4; ++i) {
    const int mb = m0 + wr + i * 16 + lq * 4;
    if (mb >= g.M) continue;
    float vb4[4][4];
    float s4[4] = {0.f, 0.f, 0.f, 0.f};
#pragma unroll
    for (int j = 0; j < 4; ++j) {
      const int n = n0 + wc + j * 16 + ln;
      const float bs = bias[n];
#pragma unroll
      for (int r = 0; r < 4; ++r) {
        const float v = acc[i][j][r] + bs;
        vb4[j][r] = v;
        s4[r] += v * v;
      }
    }
    if (seg == 2) {
#pragma unroll
      for (int j = 0; j < 4; ++j) {
        const int n = n0 + wc + j * 16 + ln;
        *(uint2*)&vTp[(size_t)(n - 2048) * NTOKA + mb] =
            pk4(f2b(vb4[j][0]), f2b(vb4[j][1]), f2b(vb4[j][2]), f2b(vb4[j][3]));
      }
    } else {
#pragma unroll
      for (int off = 1; off < 16; off <<= 1)
#pragma unroll
        for (int r = 0; r < 4; ++r) s4[r] += __shfl_xor(s4[r], off);
      float rinv[4];
#pragma unroll
      for (int r = 0; r < 4; ++r) rinv[r] = 1.f / (sqrtf(s4[r]) + 1e-6f);
      if (seg == 0) {
#pragma unroll
        for (int j = 0; j < 4; ++j) {
          const int n = n0 + wc + j * 16 + ln;
          const int hd = n & 63;
          const float sc = qS[hd], bi = qB[hd];
#pragma unroll
          for (int r = 0; r < 4; ++r)
            qbp[(size_t)(mb + r) * 1024 + n] = f2b(vb4[j][r] * rinv[r] * sc + bi);
        }
      } else {
#pragma unroll
        for (int j = 0; j < 4; ++j) {
          const int n = n0 + wc + j * 16 + ln;
          const int hd = n & 63;
          const float sc = kS[hd], bi = kB[hd];
          u16 kq[4];
#pragma unroll
          for (int r = 0; r < 4; ++r) {
            kq[r] = f2b(vb4[j][r] * rinv[r] * sc + bi);
            kbp[(size_t)(mb + r) * 1024 + (n - 1024)] = kq[r];
          }
          *(uint2*)&kTp[(size_t)(n - 1024) * NTOKA + mb] = pk4(kq[0], kq[1], kq[2], kq[3]);
        }
      }
    }
  }
}

// ---------------- fused dual-B GEMM: zg=A@G^T, zv=A@V^T ----------------
// EPI 0 (chunk loop): store f1=zv*s*(1+zg(1-s)) (C), f2=zg*s (O1[0]), h (O1[1]), hT (OT[0])
// EPI 1 (final fwd):  store h only (C)
template <int EPI>
__global__ __launch_bounds__(256, 2) void gemm_gv(GA g) {
  __shared__ u16 As[128 * 32];
  __shared__ u16 Gs[128 * 32];
  __shared__ u16 Vs[128 * 32];
  const u16* __restrict__ A = g.A[0];
  const u16* __restrict__ G = g.B[0];
  const u16* __restrict__ V = g.B[1];
  const int lda = g.lda[0], ldb = g.ldb[0];
  const int m0 = blockIdx.y * 128, n0 = blockIdx.x * 128;
  const int tid = threadIdx.x, w = tid >> 6, lane = tid & 63;
  const int wr = (w >> 1) * 64, wc = (w & 1) * 64;
  const int ln = lane & 15, lq = lane >> 4;

  f32x4 ag[4][4], av[4][4];
#pragma unroll
  for (int i = 0; i < 4; ++i)
#pragma unroll
    for (int j = 0; j < 4; ++j)
#pragma unroll
      for (int r = 0; r < 4; ++r) { ag[i][j][r] = 0.f; av[i][j][r] = 0.f; }

  const u16* Agp = A + (size_t)(m0 + 32 * w + (lane >> 2)) * lda + (lane & 3) * 8;
  const u16* Ggp = G + (size_t)(n0 + 32 * w + (lane >> 2)) * ldb + (lane & 3) * 8;
  const u16* Vgp = V + (size_t)(n0 + 32 * w + (lane >> 2)) * ldb + (lane & 3) * 8;
  u16* AsW = &As[w * 1024];
  u16* GsW = &Gs[w * 1024];
  u16* VsW = &Vs[w * 1024];
  const int nkt = g.K >> 5;

  for (int kt = 0; kt < nkt; ++kt) {
    __syncthreads();
    gload16(Agp, AsW);
    gload16(Agp + (size_t)16 * lda, AsW + 512);
    gload16(Ggp, GsW);
    gload16(Ggp + (size_t)16 * ldb, GsW + 512);
    gload16(Vgp, VsW);
    gload16(Vgp + (size_t)16 * ldb, VsW + 512);
    Agp += 32; Ggp += 32; Vgp += 32;
    __syncthreads();
    b8 af[4], gf[4], vf[4];
#pragma unroll
    for (int i = 0; i < 4; ++i) af[i] = *(const b8*)&As[(wr + i * 16 + ln) * 32 + lq * 8];
#pragma unroll
    for (int j = 0; j < 4; ++j) gf[j] = *(const b8*)&Gs[(wc + j * 16 + ln) * 32 + lq * 8];
#pragma unroll
    for (int j = 0; j < 4; ++j) vf[j] = *(const b8*)&Vs[(wc + j * 16 + ln) * 32 + lq * 8];
#pragma unroll
    for (int i = 0; i < 4; ++i)
#pragma unroll
      for (int j = 0; j < 4; ++j) {
        ag[i][j] = __builtin_amdgcn_mfma_f32_16x16x32_bf16(af[i], gf[j], ag[i][j], 0, 0, 0);
        av[i][j] = __builtin_amdgcn_mfma_f32_16x16x32_bf16(af[i], vf[j], av[i][j], 0, 0, 0);
      }
  }

  u16* F1 = (u16*)g.C[0];
  u16* F2 = g.O1[0];
  u16* Hh = g.O1[1];
  u16* HT = g.OT[0];

#pragma unroll
  for (int i = 0; i < 4; ++i) {
    const int mb = m0 + wr + i * 16 + lq * 4;
    if (mb >= g.M) continue;
#pragma unroll
    for (int j = 0; j < 4; ++j) {
      const int n = n0 + wc + j * 16 + ln;
      if (n >= g.N) continue;
      u16 hq[4];
#pragma unroll
      for (int r = 0; r < 4; ++r) {
        const int m = mb + r;
        const float zg = ag[i][j][r];
        const float zv = av[i][j][r];
        const float s = 1.f / (1.f + __expf(-zg));
        const float sw = zg * s;
        if constexpr (EPI == 0) {
          F1[(size_t)m * g.ldc + n] = f2b(zv * s * (1.f + zg * (1.f - s)));
          F2[(size_t)m * g.ldc + n] = f2b(sw);
          const u16 hb = f2b(sw * zv);
          Hh[(size_t)m * g.ldc + n] = hb;
          hq[r] = hb;
        } else {
          F1[(size_t)m * g.ldc + n] = f2b(sw * zv);
        }
      }
      if constexpr (EPI == 0)
        *(uint2*)&HT[(size_t)n * g.ldt + mb] = pk4(hq[0], hq[1], hq[2], hq[3]);
    }
  }
}

// ---------------- fused pair: gv(c+1) + grads(c) (MODE 1 fallback) ----------------
__global__ __launch_bounds__(256, 2) void fused_gg(GA ggr, GA ggv, int ysplit) {
  __shared__ u16 As[128 * 32];
  __shared__ u16 Bs[128 * 32];
  __shared__ u16 Vs[128 * 32];
  const int tid = threadIdx.x, w = tid >> 6, lane = tid & 63;
  const int wr = (w >> 1) * 64, wc = (w & 1) * 64;
  const int ln = lane & 15, lq = lane >> 4;

  if ((int)blockIdx.y < ysplit) {
    const u16* __restrict__ A = ggv.A[0];
    const u16* __restrict__ G = ggv.B[0];
    const u16* __restrict__ V = ggv.B[1];
    const int lda = ggv.lda[0], ldb = ggv.ldb[0];
    const int m0 = blockIdx.y * 128, n0 = blockIdx.x * 128;
    f32x4 ag[4][4], av[4][4];
#pragma unroll
    for (int i = 0; i < 4; ++i)
#pragma unroll
      for (int j = 0; j < 4; ++j)
#pragma unroll
        for (int r = 0; r < 4; ++r) { ag[i][j][r] = 0.f; av[i][j][r] = 0.f; }
    const u16* Agp = A + (size_t)(m0 + 32 * w + (lane >> 2)) * lda + (lane & 3) * 8;
    const u16* Ggp = G + (size_t)(n0 + 32 * w + (lane >> 2)) * ldb + (lane & 3) * 8;
    const u16* Vgp = V + (size_t)(n0 + 32 * w + (lane >> 2)) * ldb + (lane & 3) * 8;
    u16* AsW = &As[w * 1024];
    u16* GsW = &Bs[w * 1024];
    u16* VsW = &Vs[w * 1024];
    const int nkt = ggv.K >> 5;
    for (int kt = 0; kt < nkt; ++kt) {
      __syncthreads();
      gload16(Agp, AsW);
      gload16(Agp + (size_t)16 * lda, AsW + 512);
      gload16(Ggp, GsW);
      gload16(Ggp + (size_t)16 * ldb, GsW + 512);
      gload16(Vgp, VsW);
      gload16(Vgp + (size_t)16 * ldb, VsW + 512);
      Agp += 32; Ggp += 32; Vgp += 32;
      __syncthreads();
      b8 af[4], gf[4], vf[4];
#pragma unroll
      for (int i = 0; i < 4; ++i) af[i] = *(const b8*)&As[(wr + i * 16 + ln) * 32 + lq * 8];
#pragma unroll
      for (int j = 0; j < 4; ++j) gf[j] = *(const b8*)&Bs[(wc + j * 16 + ln) * 32 + lq * 8];
#pragma unroll
      for (int j = 0; j < 4; ++j) vf[j] = *(const b8*)&Vs[(wc + j * 16 + ln) * 32 + lq * 8];
#pragma unroll
      for (int i = 0; i < 4; ++i)
#pragma unroll
        for (int j = 0; j < 4; ++j) {
          ag[i][j] = __builtin_amdgcn_mfma_f32_16x16x32_bf16(af[i], gf[j], ag[i][j], 0, 0, 0);
          av[i][j] = __builtin_amdgcn_mfma_f32_16x16x32_bf16(af[i], vf[j], av[i][j], 0, 0, 0);
        }
    }
    u16* F1 = (u16*)ggv.C[0];
    u16* F2 = ggv.O1[0];
    u16* Hh = ggv.O1[1];
    u16* HT = ggv.OT[0];
#pragma unroll
    for (int i = 0; i < 4; ++i) {
      const int mb = m0 + wr + i * 16 + lq * 4;
      if (mb >= ggv.M) continue;
#pragma unroll
      for (int j = 0; j < 4; ++j) {
        const int n = n0 + wc + j * 16 + ln;
        if (n >= ggv.N) continue;
        u16 hq[4];
#pragma unroll
        for (int r = 0; r < 4; ++r) {
          const int m = mb + r;
          const float zg = ag[i][j][r];
          const float zv = av[i][j][r];
          const float s = 1.f / (1.f + __expf(-zg));
          const float sw = zg * s;
          F1[(size_t)m * ggv.ldc + n] = f2b(zv * s * (1.f + zg * (1.f - s)));
          F2[(size_t)m * ggv.ldc + n] = f2b(sw);
          const u16 hb = f2b(sw * zv);
          Hh[(size_t)m * ggv.ldc + n] = hb;
          hq[r] = hb;
        }
        *(uint2*)&HT[(size_t)n * ggv.ldt + mb] = pk4(hq[0], hq[1], hq[2], hq[3]);
      }
    }
  } else {
    const int yy = (int)blockIdx.y - ysplit;       // [0, 48)
    int bz = yy >> 3;
    const int m0 = (yy & 7) * 128, n0 = blockIdx.x * 128;
    const int koff = (bz & 1) * (ggr.K >> 1); bz >>= 1;
    const int klen = ggr.K >> 1;
    const u16* __restrict__ A = ggr.A[bz] + koff;
    const u16* __restrict__ B = ggr.B[bz] + koff;
    const int lda = ggr.lda[bz], ldb = ggr.ldb[bz];
    f32x4 acc[4][4];
#pragma unroll
    for (int i = 0; i < 4; ++i)
#pragma unroll
      for (int j = 0; j < 4; ++j)
#pragma unroll
        for (int r = 0; r < 4; ++r) acc[i][j][r] = 0.f;
    const u16* Ag = A + (size_t)(m0 + 32 * w + (lane >> 2)) * lda + (lane & 3) * 8;
    const u16* Bg = B + (size_t)(n0 + 32 * w + (lane >> 2)) * ldb + (lane & 3) * 8;
    u16* AsW = &As[w * 1024];
    u16* BsW = &Bs[w * 1024];
    const int nkt = klen >> 5;
    for (int kt = 0; kt < nkt; ++kt) {
      __syncthreads();
      gload16(Ag, AsW);
      gload16(Ag + (size_t)16 * lda, AsW + 512);
      gload16(Bg, BsW);
      gload16(Bg + (size_t)16 * ldb, BsW + 512);
      Ag += 32; Bg += 32;
      __syncthreads();
      b8 af[4], bfr[4];
#pragma unroll
      for (int i = 0; i < 4; ++i) af[i] = *(const b8*)&As[(wr + i * 16 + ln) * 32 + lq * 8];
#pragma unroll
      for (int j = 0; j < 4; ++j) bfr[j] = *(const b8*)&Bs[(wc + j * 16 + ln) * 32 + lq * 8];
#pragma unroll
      for (int i = 0; i < 4; ++i)
#pragma unroll
        for (int j = 0; j < 4; ++j)
          acc[i][j] = __builtin_amdgcn_mfma_f32_16x16x32_bf16(af[i], bfr[j], acc[i][j], 0, 0, 0);
    }
    float* Cf = (float*)ggr.C[bz];
#pragma unroll
    for (int i = 0; i < 4; ++i) {
      const int mb = m0 + wr + i * 16 + lq * 4;
      if (mb >= ggr.M) continue;
#pragma unroll
      for (int j = 0; j < 4; ++j) {
        const int n = n0 + wc + j * 16 + ln;
        if (n >= ggr.N) continue;
#pragma unroll
        for (int r = 0; r < 4; ++r) atomicAdd(&Cf[(size_t)(mb + r) * ggr.ldc + n], acc[i][j][r]);
      }
    }
  }
}

// ---------------- fused pair: gv(ci) (y<ysplit) || dh(ci-1) (y>=ysplit) ----------------
__global__ __launch_bounds__(256, 2) void fused_hg(GA gdh, GA ggv, int ysplit) {
  __shared__ u16 As[128 * 32];
  __shared__ u16 Bs[128 * 32];
  __shared__ u16 Vs[128 * 32];
  const int tid = threadIdx.x, w = tid >> 6, lane = tid & 63;
  const int wr = (w >> 1) * 64, wc = (w & 1) * 64;
  const int ln = lane & 15, lq = lane >> 4;

  if ((int)blockIdx.y < ysplit) {
    // ---------- gv path ----------
    const u16* __restrict__ A = ggv.A[0];
    const u16* __restrict__ G = ggv.B[0];
    const u16* __restrict__ V = ggv.B[1];
    const int lda = ggv.lda[0], ldb = ggv.ldb[0];
    const int m0 = blockIdx.y * 128, n0 = blockIdx.x * 128;
    f32x4 ag[4][4], av[4][4];
#pragma unroll
    for (int i = 0; i < 4; ++i)
#pragma unroll
      for (int j = 0; j < 4; ++j)
#pragma unroll
        for (int r = 0; r < 4; ++r) { ag[i][j][r] = 0.f; av[i][j][r] = 0.f; }
    const u16* Agp = A + (size_t)(m0 + 32 * w + (lane >> 2)) * lda + (lane & 3) * 8;
    const u16* Ggp = G + (size_t)(n0 + 32 * w + (lane >> 2)) * ldb + (lane & 3) * 8;
    const u16* Vgp = V + (size_t)(n0 + 32 * w + (lane >> 2)) * ldb + (lane & 3) * 8;
    u16* AsW = &As[w * 1024];
    u16* GsW = &Bs[w * 1024];
    u16* VsW = &Vs[w * 1024];
    const int nkt = ggv.K >> 5;
    for (int kt = 0; kt < nkt; ++kt) {
      __syncthreads();
      gload16(Agp, AsW);
      gload16(Agp + (size_t)16 * lda, AsW + 512);
      gload16(Ggp, GsW);
      gload16(Ggp + (size_t)16 * ldb, GsW + 512);
      gload16(Vgp, VsW);
      gload16(Vgp + (size_t)16 * ldb, VsW + 512);
      Agp += 32; Ggp += 32; Vgp += 32;
      __syncthreads();
      b8 af[4], gf[4], vf[4];
#pragma unroll
      for (int i = 0; i < 4; ++i) af[i] = *(const b8*)&As[(wr + i * 16 + ln) * 32 + lq * 8];
#pragma unroll
      for (int j = 0; j < 4; ++j) gf[j] = *(const b8*)&Bs[(wc + j * 16 + ln) * 32 + lq * 8];
#pragma unroll
      for (int j = 0; j < 4; ++j) vf[j] = *(const b8*)&Vs[(wc + j * 16 + ln) * 32 + lq * 8];
#pragma unroll
      for (int i = 0; i < 4; ++i)
#pragma unroll
        for (int j = 0; j < 4; ++j) {
          ag[i][j] = __builtin_amdgcn_mfma_f32_16x16x32_bf16(af[i], gf[j], ag[i][j], 0, 0, 0);
          av[i][j] = __builtin_amdgcn_mfma_f32_16x16x32_bf16(af[i], vf[j], av[i][j], 0, 0, 0);
        }
    }
    u16* F1 = (u16*)ggv.C[0];
    u16* F2 = ggv.O1[0];
    u16* Hh = ggv.O1[1];
    u16* HT = ggv.OT[0];
#pragma unroll
    for (int i = 0; i < 4; ++i) {
      const int mb = m0 + wr + i * 16 + lq * 4;
      if (mb >= ggv.M) continue;
#pragma unroll
      for (int j = 0; j < 4; ++j) {
        const int n = n0 + wc + j * 16 + ln;
        u16 hq[4];
#pragma unroll
        for (int r = 0; r < 4; ++r) {
          const int m = mb + r;
          const float zg = ag[i][j][r];
          const float zv = av[i][j][r];
          const float s = 1.f / (1.f + __expf(-zg));
          const float sw = zg * s;
          F1[(size_t)m * ggv.ldc + n] = f2b(zv * s * (1.f + zg * (1.f - s)));
          F2[(size_t)m * ggv.ldc + n] = f2b(sw);
          const u16 hb = f2b(sw * zv);
          Hh[(size_t)m * ggv.ldc + n] = hb;
          hq[r] = hb;
        }
        *(uint2*)&HT[(size_t)n * ggv.ldt + mb] = pk4(hq[0], hq[1], hq[2], hq[3]);
      }
    }
  } else {
    // ---------- dh path ----------
    const int m0 = ((int)blockIdx.y - ysplit) * 128, n0 = blockIdx.x * 128;
    const u16* __restrict__ A = gdh.A[0];
    const u16* __restrict__ B = gdh.B[0];
    const int lda = gdh.lda[0], ldb = gdh.ldb[0];
    f32x4 acc[4][4];
#pragma unroll
    for (int i = 0; i < 4; ++i)
#pragma unroll
      for (int j = 0; j < 4; ++j)
#pragma unroll
        for (int r = 0; r < 4; ++r) acc[i][j][r] = 0.f;
    const u16* Ag = A + (size_t)(m0 + 32 * w + (lane >> 2)) * lda + (lane & 3) * 8;
    const u16* Bg = B + (size_t)(n0 + 32 * w + (lane >> 2)) * ldb + (lane & 3) * 8;
    u16* AsW = &As[w * 1024];
    u16* BsW = &Bs[w * 1024];
    const int nkt = gdh.K >> 5;
    for (int kt = 0; kt < nkt; ++kt) {
      __syncthreads();
      gload16(Ag, AsW);
      gload16(Ag + (size_t)16 * lda, AsW + 512);
      gload16(Bg, BsW);
      gload16(Bg + (size_t)16 * ldb, BsW + 512);
      Ag += 32; Bg += 32;
      __syncthreads();
      b8 af[4], bfr[4];
#pragma unroll
      for (int i = 0; i < 4; ++i) af[i] = *(const b8*)&As[(wr + i * 16 + ln) * 32 + lq * 8];
#pragma unroll
      for (int j = 0; j < 4; ++j) bfr[j] = *(const b8*)&Bs[(wc + j * 16 + ln) * 32 + lq * 8];
#pragma unroll
      for (int i = 0; i < 4; ++i)
#pragma unroll
        for (int j = 0; j < 4; ++j)
          acc[i][j] = __builtin_amdgcn_mfma_f32_16x16x32_bf16(af[i], bfr[j], acc[i][j], 0, 0, 0);
    }
    u16* Cb = (u16*)gdh.C[0];
    u16* O1 = gdh.O1[0];
    const u16* E0b = (const u16*)gdh.E0[0];
    const u16* E1b = gdh.E1[0];
#pragma unroll
    for (int i = 0; i < 4; ++i) {
      const int mb = m0 + wr + i * 16 + lq * 4;
      if (mb >= gdh.M) continue;
#pragma unroll
      for (int j = 0; j < 4; ++j) {
        const int n = n0 + wc + j * 16 + ln;
        u16 cq[4], oq[4];
#pragma unroll
        for (int r = 0; r < 4; ++r) {
          const int m = mb + r;
          const float f1 = b2f(E0b[(size_t)m * gdh.lde0 + n]);
          const float f2 = b2f(E1b[(size_t)m * gdh.lde1 + n]);
          cq[r] = f2b(acc[i][j][r] * f1);
          oq[r] = f2b(acc[i][j][r] * f2);
        }
        *(uint2*)&Cb[(size_t)n * gdh.ldt + mb] = pk4(cq[0], cq[1], cq[2], cq[3]);
        *(uint2*)&O1[(size_t)n * gdh.ldt + mb] = pk4(oq[0], oq[1], oq[2], oq[3]);
      }
    }
  }
}

// ---------------- fused pair: grads(ci-1) [bid<nGr, no split-K] || dpred(ci) [rest] ----------------
// FIRST=1: grads STOREs gAll (first chunk); FIRST=0: atomicAdd
template <int FIRST>
__global__ __launch_bounds__(256, 2) void fused_gd(GA ggr, GA gdp, int nGr, int dpx) {
  __shared__ u16 As[128 * 32];
  __shared__ u16 Bs[128 * 32];
  const int tid = threadIdx.x, w = tid >> 6, lane = tid & 63;
  const int ln = lane & 15, lq = lane >> 4;
  const int bid = blockIdx.x;

  if (bid < nGr) {
    // grads path, no split-K: nGr = 32*8*3 = 768
    const int wr = (w >> 1) * 64, wc = (w & 1) * 64;
    const int n0 = (bid & 31) * 128;
    const int rest = bid >> 5;                // [0,24)
    const int m0 = (rest & 7) * 128;
    const int bz = rest >> 3;                 // [0,3)
    const u16* __restrict__ A = ggr.A[bz];
    const u16* __restrict__ B = ggr.B[bz];
    const int lda = ggr.lda[bz], ldb = ggr.ldb[bz];
    f32x4 acc[4][4];
#pragma unroll
    for (int i = 0; i < 4; ++i)
#pragma unroll
      for (int j = 0; j < 4; ++j)
#pragma unroll
        for (int r = 0; r < 4; ++r) acc[i][j][r] = 0.f;
    const u16* Ag = A + (size_t)(m0 + 32 * w + (lane >> 2)) * lda + (lane & 3) * 8;
    const u16* Bg = B + (size_t)(n0 + 32 * w + (lane >> 2)) * ldb + (lane & 3) * 8;
    u16* AsW = &As[w * 1024];
    u16* BsW = &Bs[w * 1024];
    const int nkt = ggr.K >> 5;
    for (int kt = 0; kt < nkt; ++kt) {
      __syncthreads();
      gload16(Ag, AsW);
      gload16(Ag + (size_t)16 * lda, AsW + 512);
      gload16(Bg, BsW);
      gload16(Bg + (size_t)16 * ldb, BsW + 512);
      Ag += 32; Bg += 32;
      __syncthreads();
      b8 af[4], bfr[4];
#pragma unroll
      for (int i = 0; i < 4; ++i) af[i] = *(const b8*)&As[(wr + i * 16 + ln) * 32 + lq * 8];
#pragma unroll
      for (int j = 0; j < 4; ++j) bfr[j] = *(const b8*)&Bs[(wc + j * 16 + ln) * 32 + lq * 8];
#pragma unroll
      for (int i = 0; i < 4; ++i)
#pragma unroll
        for (int j = 0; j < 4; ++j)
          acc[i][j] = __builtin_amdgcn_mfma_f32_16x16x32_bf16(af[i], bfr[j], acc[i][j], 0, 0, 0);
    }
    float* Cf = (float*)ggr.C[bz];
#pragma unroll
    for (int i = 0; i < 4; ++i) {
      const int mb = m0 + wr + i * 16 + lq * 4;
#pragma unroll
      for (int j = 0; j < 4; ++j) {
        const int n = n0 + wc + j * 16 + ln;
#pragma unroll
        for (int r = 0; r < 4; ++r) {
          if constexpr (FIRST) Cf[(size_t)(mb + r) * ggr.ldc + n] = acc[i][j][r];
          else atomicAdd(&Cf[(size_t)(mb + r) * ggr.ldc + n], acc[i][j][r]);
        }
      }
    }
  } else {
    // dpred path (gemm64<2> body)
    const int wr = (w >> 1) * 32, wc = (w & 1) * 32;
    const int l = bid - nGr;
    const int n0 = (l % dpx) * 64;
    const int m0 = (l / dpx) * 64;
    const u16* __restrict__ A = gdp.A[0];
    const u16* __restrict__ B = gdp.B[0];
    const int lda = gdp.lda[0], ldb = gdp.ldb[0];
    f32x4 acc[2][2];
#pragma unroll
    for (int i = 0; i < 2; ++i)
#pragma unroll
      for (int j = 0; j < 2; ++j)
#pragma unroll
        for (int r = 0; r < 4; ++r) acc[i][j][r] = 0.f;
    const u16* Ag = A + (size_t)(m0 + 16 * w + (lane >> 2)) * lda + (lane & 3) * 8;
    const u16* Bg = B + (size_t)(n0 + 16 * w + (lane >> 2)) * ldb + (lane & 3) * 8;
    u16* AsW = &As[w * 512];
    u16* BsW = &Bs[w * 512];
    const int nkt = gdp.K >> 5;
    for (int kt = 0; kt < nkt; ++kt) {
      __syncthreads();
      gload16(Ag, AsW);
      gload16(Bg, BsW);
      Ag += 32; Bg += 32;
      __syncthreads();
      b8 af[2], bfr[2];
#pragma unroll
      for (int i = 0; i < 2; ++i) af[i] = *(const b8*)&As[(wr + i * 16 + ln) * 32 + lq * 8];
#pragma unroll
      for (int j = 0; j < 2; ++j) bfr[j] = *(const b8*)&Bs[(wc + j * 16 + ln) * 32 + lq * 8];
#pragma unroll
      for (int i = 0; i < 2; ++i)
#pragma unroll
        for (int j = 0; j < 2; ++j)
          acc[i][j] = __builtin_amdgcn_mfma_f32_16x16x32_bf16(af[i], bfr[j], acc[i][j], 0, 0, 0);
    }
    u16* Cb = (u16*)gdp.C[0];
    u16* OT = gdp.OT[0];
    const u16* E0b = (const u16*)gdp.E0[0];
#pragma unroll
    for (int i = 0; i < 2; ++i) {
      const int mb = m0 + wr + i * 16 + lq * 4;
#pragma unroll
      for (int j = 0; j < 2; ++j) {
        const int n = n0 + wc + j * 16 + ln;
        if (n >= gdp.N) continue;
        u16 cq[4];
#pragma unroll
        for (int r = 0; r < 4; ++r) {
          const int m = mb + r;
          const u16 ub = f2b((acc[i][j][r] - b2f(E0b[(size_t)m * gdp.lde0 + n])) * gdp.p0);
          Cb[(size_t)m * gdp.ldc + n] = ub;
          cq[r] = ub;
        }
        *(uint2*)&OT[(size_t)n * gdp.ldt + mb] = pk4(cq[0], cq[1], cq[2], cq[3]);
      }
    }
  }
}

// ---------------- fused pair: T = W@A (y<16) || MT' = nsa*MT + MT@W (y>=16) ----------------
__global__ __launch_bounds__(256, 2) void fused_mt(GA gt, GA gm) {
  __shared__ u16 As[64 * 32];
  __shared__ u16 Bs[64 * 32];
  const int bz = blockIdx.z;
  const int mp = ((int)blockIdx.y >= 16) ? 1 : 0;
  const GA& g = mp ? gm : gt;
  const int m0 = ((int)blockIdx.y - (mp ? 16 : 0)) * 64, n0 = blockIdx.x * 64;
  const u16* __restrict__ A = g.A[bz];
  const u16* __restrict__ B = g.B[bz];
  const int lda = g.lda[bz], ldb = g.ldb[bz];
  const int tid = threadIdx.x, w = tid >> 6, lane = tid & 63;
  const int wr = (w >> 1) * 32, wc = (w & 1) * 32;
  const int ln = lane & 15, lq = lane >> 4;

  f32x4 acc[2][2];
#pragma unroll
  for (int i = 0; i < 2; ++i)
#pragma unroll
    for (int j = 0; j < 2; ++j)
#pragma unroll
      for (int r = 0; r < 4; ++r) acc[i][j][r] = 0.f;

  const u16* Ag = A + (size_t)(m0 + 16 * w + (lane >> 2)) * lda + (lane & 3) * 8;
  const u16* Bg = B + (size_t)(n0 + 16 * w + (lane >> 2)) * ldb + (lane & 3) * 8;
  u16* AsW = &As[w * 512];
  u16* BsW = &Bs[w * 512];
  const int nkt = g.K >> 5;

  for (int kt = 0; kt < nkt; ++kt) {
    __syncthreads();
    gload16(Ag, AsW);
    gload16(Bg, BsW);
    Ag += 32; Bg += 32;
    __syncthreads();
    b8 af[2], bfr[2];
#pragma unroll
    for (int i = 0; i < 2; ++i) af[i] = *(const b8*)&As[(wr + i * 16 + ln) * 32 + lq * 8];
#pragma unroll
    for (int j = 0; j < 2; ++j) bfr[j] = *(const b8*)&Bs[(wc + j * 16 + ln) * 32 + lq * 8];
#pragma unroll
    for (int i = 0; i < 2; ++i)
#pragma unroll
      for (int j = 0; j < 2; ++j)
        acc[i][j] = __builtin_amdgcn_mfma_f32_16x16x32_bf16(af[i], bfr[j], acc[i][j], 0, 0, 0);
  }

  u16* Cb = (u16*)g.C[bz];
  const u16* E0b = (const u16*)g.E0[bz];
#pragma unroll
  for (int i = 0; i < 2; ++i) {
    const int mb = m0 + wr + i * 16 + lq * 4;
#pragma unroll
    for (int j = 0; j < 2; ++j) {
      const int n = n0 + wc + j * 16 + ln;
      if (mp) {
#pragma unroll
        for (int r = 0; r < 4; ++r) {
          const int m = mb + r;
          Cb[(size_t)m * g.ldc + n] = f2b(g.p0 * b2f(E0b[(size_t)m * g.lde0 + n]) + acc[i][j][r]);
        }
      } else {
#pragma unroll
        for (int r = 0; r < 4; ++r) Cb[(size_t)(mb + r) * g.ldc + n] = f2b(acc[i][j][r]);
      }
    }
  }
}

// ---------------- fused pair: final gv<1> (y<ysplit) || PWt gemm_bt<0> (y>=ysplit) ----------------
__global__ __launch_bounds__(256, 2) void fused_pg(GA gp, GA ggv, int ysplit) {
  __shared__ u16 As[128 * 32];
  __shared__ u16 Bs[128 * 32];
  __shared__ u16 Vs[128 * 32];
  const int tid = threadIdx.x, w = tid >> 6, lane = tid & 63;
  const int wr = (w >> 1) * 64, wc = (w & 1) * 64;
  const int ln = lane & 15, lq = lane >> 4;

  if ((int)blockIdx.y < ysplit) {
    const u16* __restrict__ A = ggv.A[0];
    const u16* __restrict__ G = ggv.B[0];
    const u16* __restrict__ V = ggv.B[1];
    const int lda = ggv.lda[0], ldb = ggv.ldb[0];
    const int m0 = blockIdx.y * 128, n0 = blockIdx.x * 128;
    f32x4 ag[4][4], av[4][4];
#pragma unroll
    for (int i = 0; i < 4; ++i)
#pragma unroll
      for (int j = 0; j < 4; ++j)
#pragma unroll
        for (int r = 0; r < 4; ++r) { ag[i][j][r] = 0.f; av[i][j][r] = 0.f; }
    const u16* Agp = A + (size_t)(m0 + 32 * w + (lane >> 2)) * lda + (lane & 3) * 8;
    const u16* Ggp = G + (size_t)(n0 + 32 * w + (lane >> 2)) * ldb + (lane & 3) * 8;
    const u16* Vgp = V + (size_t)(n0 + 32 * w + (lane >> 2)) * ldb + (lane & 3) * 8;
    u16* AsW = &As[w * 1024];
    u16* GsW = &Bs[w * 1024];
    u16* VsW = &Vs[w * 1024];
    const int nkt = ggv.K >> 5;
    for (int kt = 0; kt < nkt; ++kt) {
      __syncthreads();
      gload16(Agp, AsW);
      gload16(Agp + (size_t)16 * lda, AsW + 512);
      gload16(Ggp, GsW);
      gload16(Ggp + (size_t)16 * ldb, GsW + 512);
      gload16(Vgp, VsW);
      gload16(Vgp + (size_t)16 * ldb, VsW + 512);
      Agp += 32; Ggp += 32; Vgp += 32;
      __syncthreads();
      b8 af[4], gf[4], vf[4];
#pragma unroll
      for (int i = 0; i < 4; ++i) af[i] = *(const b8*)&As[(wr + i * 16 + ln) * 32 + lq * 8];
#pragma unroll
      for (int j = 0; j < 4; ++j) gf[j] = *(const b8*)&Bs[(wc + j * 16 + ln) * 32 + lq * 8];
#pragma unroll
      for (int j = 0; j < 4; ++j) vf[j] = *(const b8*)&Vs[(wc + j * 16 + ln) * 32 + lq * 8];
#pragma unroll
      for (int i = 0; i < 4; ++i)
#pragma unroll
        for (int j = 0; j < 4; ++j) {
          ag[i][j] = __builtin_amdgcn_mfma_f32_16x16x32_bf16(af[i], gf[j], ag[i][j], 0, 0, 0);
          av[i][j] = __builtin_amdgcn_mfma_f32_16x16x32_bf16(af[i], vf[j], av[i][j], 0, 0, 0);
        }
    }
    u16* Hh = (u16*)ggv.C[0];
#pragma unroll
    for (int i = 0; i < 4; ++i) {
      const int mb = m0 + wr + i * 16 + lq * 4;
      if (mb >= ggv.M) continue;
#pragma unroll
      for (int j = 0; j < 4; ++j) {
        const int n = n0 + wc + j * 16 + ln;
#pragma unroll
        for (int r = 0; r < 4; ++r) {
          const float zg = ag[i][j][r];
          const float zv = av[i][j][r];
          const float s = 1.f / (1.f + __expf(-zg));
          Hh[(size_t)(mb + r) * ggv.ldc + n] = f2b(zg * s * zv);
        }
      }
    }
  } else {
    const int m0 = ((int)blockIdx.y - ysplit) * 128, n0 = blockIdx.x * 128;
    const u16* __restrict__ A = gp.A[0];
    const u16* __restrict__ B = gp.B[0];
    const int lda = gp.lda[0], ldb = gp.ldb[0];
    f32x4 acc[4][4];
#pragma unroll
    for (int i = 0; i < 4; ++i)
#pragma unroll
      for (int j = 0; j < 4; ++j)
#pragma unroll
        for (int r = 0; r < 4; ++r) acc[i][j][r] = 0.f;
    const u16* Ag = A + (size_t)(m0 + 32 * w + (lane >> 2)) * lda + (lane & 3) * 8;
    const u16* Bg = B + (size_t)(n0 + 32 * w + (lane >> 2)) * ldb + (lane & 3) * 8;
    u16* AsW = &As[w * 1024];
    u16* BsW = &Bs[w * 1024];
    const int nkt = gp.K >> 5;
    for (int kt = 0; kt < nkt; ++kt) {
      __syncthreads();
      gload16(Ag, AsW);
      gload16(Ag + (size_t)16 * lda, AsW + 512);
      gload16(Bg, BsW);
      gload16(Bg + (size_t)16 * ldb, BsW + 512);
      Ag += 32; Bg += 32;
      __syncthreads();
      b8 af[4], bfr[4];
#pragma unroll
      for (int i = 0; i < 4; ++i) af[i] = *(const b8*)&As[(wr + i * 16 + ln) * 32 + lq * 8];
#pragma unroll
      for (int j = 0; j < 4; ++j) bfr[j] = *(const b8*)&Bs[(wc + j * 16 + ln) * 32 + lq * 8];
#pragma unroll
      for (int i = 0; i < 4; ++i)
#pragma unroll
        for (int j = 0; j < 4; ++j)
          acc[i][j] = __builtin_amdgcn_mfma_f32_16x16x32_bf16(af[i], bfr[j], acc[i][j], 0, 0, 0);
    }
    u16* Cb = (u16*)gp.C[0];
#pragma unroll
    for (int i = 0; i < 4; ++i) {
      const int mb = m0 + wr + i * 16 + lq * 4;
#pragma unroll
      for (int j = 0; j < 4; ++j) {
        const int n = n0 + wc + j * 16 + ln;
#pragma unroll
        for (int r = 0; r < 4; ++r) Cb[(size_t)(mb + r) * gp.ldc + n] = f2b(acc[i][j][r]);
      }
    }
  }
}

// ---------------- 64x64 tile GEMM ----------------
// EPI: 0 Cb=acc | 2 v=(acc-E0b)*p0 -> Cb + OT(T-pack)
//      10 sym: Cb=acc + mirror | 11 sym: Cb=p0*E0b+p1*acc + mirror
//      12 sym: Cb=p0*E0b + p1*(E1[m,n]+E1[n,m]) + acc + mirror
//      13 sym: W=p0*E0b+p1*acc + mirror, AND M0=W+nsa*I -> OT (+ mirror)
//      15 Cb=p0*E0b[n,m] + acc
template <int EPI>
__global__ __launch_bounds__(256, 2) void gemm64(GA g) {
  if constexpr (EPI == 10 || EPI == 11 || EPI == 12 || EPI == 13) {
    if (blockIdx.x > blockIdx.y) return;
  }
  __shared__ u16 As[64 * 32];
  __shared__ u16 Bs[64 * 32];
  const int bz = blockIdx.z;
  const u16* __restrict__ A = g.A[bz];
  const u16* __restrict__ B = g.B[bz];
  const int lda = g.lda[bz], ldb = g.ldb[bz];
  const int m0 = blockIdx.y * 64, n0 = blockIdx.x * 64;
  const int tid = threadIdx.x, w = tid >> 6, lane = tid & 63;
  const int wr = (w >> 1) * 32, wc = (w & 1) * 32;
  const int ln = lane & 15, lq = lane >> 4;

  f32x4 acc[2][2];
#pragma unroll
  for (int i = 0; i < 2; ++i)
#pragma unroll
    for (int j = 0; j < 2; ++j)
#pragma unroll
      for (int r = 0; r < 4; ++r) acc[i][j][r] = 0.f;

  const u16* Ag = A + (size_t)(m0 + 16 * w + (lane >> 2)) * lda + (lane & 3) * 8;
  const u16* Bg = B + (size_t)(n0 + 16 * w + (lane >> 2)) * ldb + (lane & 3) * 8;
  u16* AsW = &As[w * 512];
  u16* BsW = &Bs[w * 512];
  const int nkt = g.K >> 5;

  for (int kt = 0; kt < nkt; ++kt) {
    __syncthreads();
    gload16(Ag, AsW);
    gload16(Bg, BsW);
    Ag += 32; Bg += 32;
    __syncthreads();
    b8 af[2], bfr[2];
#pragma unroll
    for (int i = 0; i < 2; ++i) af[i] = *(const b8*)&As[(wr + i * 16 + ln) * 32 + lq * 8];
#pragma unroll
    for (int j = 0; j < 2; ++j) bfr[j] = *(const b8*)&Bs[(wc + j * 16 + ln) * 32 + lq * 8];
#pragma unroll
    for (int i = 0; i < 2; ++i)
#pragma unroll
      for (int j = 0; j < 2; ++j)
        acc[i][j] = __builtin_amdgcn_mfma_f32_16x16x32_bf16(af[i], bfr[j], acc[i][j], 0, 0, 0);
  }

  u16* Cb = (u16*)g.C[bz];
  u16* OT = g.OT[bz];
  const u16* E0b = (const u16*)g.E0[bz];
  const u16* E1b = g.E1[bz];
  const bool offdiag = (blockIdx.x != blockIdx.y);

#pragma unroll
  for (int i = 0; i < 2; ++i) {
    const int mb = m0 + wr + i * 16 + lq * 4;
    if (mb >= g.M) continue;
#pragma unroll
    for (int j = 0; j < 2; ++j) {
      const int n = n0 + wc + j * 16 + ln;
      if (n >= g.N) continue;
      float vv[4];
#pragma unroll
      for (int r = 0; r < 4; ++r) vv[r] = acc[i][j][r];
      if constexpr (EPI == 0) {
#pragma unroll
        for (int r = 0; r < 4; ++r) Cb[(size_t)(mb + r) * g.ldc + n] = f2b(vv[r]);
      } else if constexpr (EPI == 2) {
        u16 cq[4];
#pragma unroll
        for (int r = 0; r < 4; ++r) {
          const int m = mb + r;
          const u16 ub = f2b((vv[r] - b2f(E0b[(size_t)m * g.lde0 + n])) * g.p0);
          Cb[(size_t)m * g.ldc + n] = ub;
          cq[r] = ub;
        }
        *(uint2*)&OT[(size_t)n * g.ldt + mb] = pk4(cq[0], cq[1], cq[2], cq[3]);
      } else if constexpr (EPI == 10) {
        u16 cq[4];
#pragma unroll
        for (int r = 0; r < 4; ++r) {
          cq[r] = f2b(vv[r]);
          Cb[(size_t)(mb + r) * g.ldc + n] = cq[r];
        }
        if (offdiag)
          *(uint2*)&Cb[(size_t)n * g.ldc + mb] = pk4(cq[0], cq[1], cq[2], cq[3]);
      } else if constexpr (EPI == 11) {
        u16 cq[4];
#pragma unroll
        for (int r = 0; r < 4; ++r) {
          cq[r] = f2b(g.p0 * b2f(E0b[(size_t)(mb + r) * g.lde0 + n]) + g.p1 * vv[r]);
          Cb[(size_t)(mb + r) * g.ldc + n] = cq[r];
        }
        if (offdiag)
          *(uint2*)&Cb[(size_t)n * g.ldc + mb] = pk4(cq[0], cq[1], cq[2], cq[3]);
      } else if constexpr (EPI == 12) {
        const uint2 t2u = *(const uint2*)&E1b[(size_t)n * g.lde1 + mb];
        const float t2v[4] = { b2f((u16)(t2u.x & 0xffff)), b2f((u16)(t2u.x >> 16)),
                               b2f((u16)(t2u.y & 0xffff)), b2f((u16)(t2u.y >> 16)) };
        u16 cq[4];
#pragma unroll
        for (int r = 0; r < 4; ++r) {
          const int m = mb + r;
          const float t1 = b2f(E1b[(size_t)m * g.lde1 + n]);
          const float a0 = b2f(E0b[(size_t)m * g.lde0 + n]);
          cq[r] = f2b(g.p0 * a0 + g.p1 * (t1 + t2v[r]) + vv[r]);
          Cb[(size_t)m * g.ldc + n] = cq[r];
        }
        if (offdiag)
          *(uint2*)&Cb[(size_t)n * g.ldc + mb] = pk4(cq[0], cq[1], cq[2], cq[3]);
      } else if constexpr (EPI == 13) {
        u16 cq[4], mq[4];
#pragma unroll
        for (int r = 0; r < 4; ++r) {
          const int m = mb + r;
          cq[r] = f2b(g.p0 * b2f(E0b[(size_t)m * g.lde0 + n]) + g.p1 * vv[r]);
          Cb[(size_t)m * g.ldc + n] = cq[r];
          float wv = b2f(cq[r]);
          if (m == n) wv += 3.4445f;
          mq[r] = f2b(wv);
          OT[(size_t)m * 1024 + n] = mq[r];
        }
        if (offdiag) {
          *(uint2*)&Cb[(size_t)n * g.ldc + mb] = pk4(cq[0], cq[1], cq[2], cq[3]);
          *(uint2*)&OT[(size_t)n * 1024 + mb] = pk4(mq[0], mq[1], mq[2], mq[3]);
        }
      } else if constexpr (EPI == 15) {
        const uint2 eu = *(const uint2*)&E0b[(size_t)n * g.lde0 + mb];
        const float e4[4] = { b2f((u16)(eu.x & 0xffff)), b2f((u16)(eu.x >> 16)),
                              b2f((u16)(eu.y & 0xffff)), b2f((u16)(eu.y >> 16)) };
#pragma unroll
        for (int r = 0; r < 4; ++r)
          Cb[(size_t)(mb + r) * g.ldc + n] = f2b(g.p0 * e4[r] + vv[r]);
      }
    }
  }
}

__global__ __launch_bounds__(256) void tr_f32b(const float* __restrict__ in, u16* __restrict__ out,
                                               int Cin, int Rtot) {
  __shared__ u16 t[32][33];
  const int c0 = blockIdx.x * 32, r0 = blockIdx.y * 32;
  const int tx = threadIdx.x, ty = threadIdx.y;
#pragma unroll
  for (int yy = 0; yy < 4; ++yy) {
    const int rr = ty * 4 + yy;
    t[rr][tx] = f2b(in[(size_t)(r0 + rr) * Cin + c0 + tx]);
  }
  __syncthreads();
#pragma unroll
  for (int yy = 0; yy < 4; ++yy) {
    const int cc = ty * 4 + yy;
    out[(size_t)(c0 + cc) * Rtot + r0 + tx] = t[tx][cc];
  }
}

__global__ void cvt_k(const float* __restrict__ in, u16* __restrict__ out, int n) {
  const int i = blockIdx.x * 256 + threadIdx.x;
  if (i < n) out[i] = f2b(in[i]);
}

__global__ void diag_k(float* __restrict__ out, int n, float val) {
  const int i = blockIdx.x * 256 + threadIdx.x;
  if (i < n) out[i] = val;
}

// zero token-tail cols [NTOK, NTOKA) of kT / vT
__global__ void zero_tail(u16* a, u16* b) {
  u16* p = (blockIdx.y ? b : a) + (size_t)blockIdx.x * NTOKA + NTOK;
  p[threadIdx.x & 255] = 0;
  if (threadIdx.x < 16) p[256 + threadIdx.x] = 0;
}

__global__ __launch_bounds__(256) void sumsq_k(const float* __restrict__ g, float* __restrict__ out) {
  const int b = blockIdx.y;
  const float* p = g + (size_t)b * PMi;
  float s = 0.f;
  for (int i = blockIdx.x * 256 + threadIdx.x; i < PMi; i += gridDim.x * 256) {
    float v = p[i]; s += v * v;
  }
  for (int off = 32; off > 0; off >>= 1) s += __shfl_xor(s, off);
  __shared__ float red[4];
  if ((threadIdx.x & 63) == 0) red[threadIdx.x >> 6] = s;
  __syncthreads();
  if (threadIdx.x == 0) atomicAdd(out + b, red[0] + red[1] + red[2] + red[3]);
}

__global__ __launch_bounds__(256) void scale_tr(const float* __restrict__ g, const float* __restrict__ ss,
                                                u16* __restrict__ Xb, u16* __restrict__ XbT) {
  const int b = blockIdx.z;
  __shared__ u16 t[32][33];
  const float r = 1.f / (sqrtf(ss[b]) + 1e-7f);
  const float* G = g + (size_t)b * PMi;
  u16* X = Xb + (size_t)b * PMi;
  u16* XT = XbT + (size_t)b * PMi;
  const int j0 = blockIdx.x * 32, i0 = blockIdx.y * 32;
  const int tx = threadIdx.x, ty = threadIdx.y;
#pragma unroll
  for (int yy = 0; yy < 4; ++yy) {
    const int rr = ty * 4 + yy;
    const u16 v = f2b(G[(size_t)(i0 + rr) * 4096 + j0 + tx] * r);
    X[(size_t)(i0 + rr) * 4096 + j0 + tx] = v;
    t[rr][tx] = v;
  }
  __syncthreads();
#pragma unroll
  for (int yy = 0; yy < 4; ++yy) {
    const int cc = ty * 4 + yy;
    XT[(size_t)(j0 + cc) * 1024 + i0 + tx] = t[tx][cc];
  }
}

static GA mk(const u16* A, const u16* B, void* C, int M, int N, int K,
             int lda, int ldb, int ldc) {
  GA a{};
  a.A[0] = a.A[1] = a.A[2] = A;
  a.B[0] = a.B[1] = a.B[2] = B;
  a.C[0] = a.C[1] = a.C[2] = C;
  a.lda[0] = a.lda[1] = a.lda[2] = lda;
  a.ldb[0] = a.ldb[1] = a.ldb[2] = ldb;
  a.M = M; a.N = N; a.K = K; a.ldc = ldc;
  return a;
}

extern "C" void kernel_launch(void* const* d_in, const int* in_sizes, int n_in,
                              void* d_out, int out_size, void* d_ws, size_t ws_size,
                              hipStream_t stream) {
  (void)in_sizes; (void)n_in;
  const float* x      = (const float*)d_in[0];
  const float* qkv_w  = (const float*)d_in[1];
  const float* qkv_b  = (const float*)d_in[2];
  const float* qn_s   = (const float*)d_in[3];
  const float* qn_b   = (const float*)d_in[4];
  const float* kn_s   = (const float*)d_in[5];
  const float* kn_b   = (const float*)d_in[6];
  const float* g_gate = (const float*)d_in[7];
  const float* g_val  = (const float*)d_in[8];
  const float* g_proj = (const float*)d_in[9];
  const float* proj_w = (const float*)d_in[10];
  const float* proj_b = (const float*)d_in[11];
  float* out = (float*)d_out;

  const size_t PM = PMi;
  const size_t TD = (size_t)NTOKA * 1024;
  const size_t PERS = 127926528ull;

  auto needD = [&](int chk) {
    return PERS + 9ull * (size_t)chk * 8192 + 4ull * (size_t)chk * 2048 + 50331648ull + 8192;
  };
  auto needP = [&](int chk) {
    return PERS + 7ull * (size_t)chk * 8192 + 2ull * (size_t)chk * 2048 + 50331648ull + 8192;
  };
  auto needU = [&](int chk) {
    return PERS + 5ull * (size_t)chk * 8192 + 2ull * (size_t)chk * 2048 + 50331648ull + 4096;
  };
  int CHKr, MODE;
  if      (ws_size >= needD(5632)) { CHKr = 5632; MODE = 2; }
  else if (ws_size >= needD(4096)) { CHKr = 4096; MODE = 2; }
  else if (ws_size >= needP(5632)) { CHKr = 5632; MODE = 1; }
  else if (ws_size >= needU(5632)) { CHKr = 5632; MODE = 0; }
  else if (ws_size >= needP(2816)) { CHKr = 2816; MODE = 1; }
  else if (ws_size >= needP(2048)) { CHKr = 2048; MODE = 1; }
  else if (ws_size >= needU(1408)) { CHKr = 1408; MODE = 0; }
  else {
    diag_k<<<dim3((out_size + 255) / 256), dim3(256), 0, stream>>>(out, out_size,
                                                                   (float)(ws_size >> 20));
    return;
  }

  char* p = (char*)d_ws;
  auto carve = [&](size_t bytes) { char* r = p; p += (bytes + 255) & ~(size_t)255; return (void*)r; };
  auto cdiv = [](int a, int b) { return (a + b - 1) / b; };
  auto mini = [](int a, int b) { return a < b ? a : b; };

  // ---- persistent (127.93 MB) ----
  u16* Gt     = (u16*)carve(PM * 2);
  u16* Vt     = (u16*)carve(PM * 2);
  u16* Pt     = (u16*)carve(PM * 2);
  u16* Pb     = (u16*)carve(PM * 2);
  u16* projWt = (u16*)carve(1048576ull * 2);
  u16* qb     = (u16*)carve(TD * 2);
  u16* kb     = (u16*)carve(TD * 2);
  u16* vT     = (u16*)carve(TD * 2);
  u16* kT     = (u16*)carve(TD * 2);
  float* ssq  = (float*)carve(256);
  char* arena = p;

  // P0 staging
  u16* xb    = (u16*)arena;
  u16* qkvWt = (u16*)(arena + 23068672);
  // P1 backward per chunk
  const size_t CB = (size_t)CHKr * 4096 * 2;
  const size_t DP = (size_t)CHKr * 1024 * 2;
  u16 *f1A[2], *f2A[2], *hhA[2], *hTA[2], *dpTA[2], *dpBA[2], *dzvT;
  float* gAll;
  if (MODE == 2) {
    f1A[0] = (u16*)(arena + 0 * CB);  f2A[0] = (u16*)(arena + 1 * CB);
    hhA[0] = (u16*)(arena + 2 * CB);  hTA[0] = (u16*)(arena + 3 * CB);
    f1A[1] = (u16*)(arena + 4 * CB);  f2A[1] = (u16*)(arena + 5 * CB);
    hhA[1] = (u16*)(arena + 6 * CB);  hTA[1] = (u16*)(arena + 7 * CB);
    dzvT   = (u16*)(arena + 8 * CB);
    dpTA[0] = (u16*)(arena + 9 * CB);          dpBA[0] = (u16*)(arena + 9 * CB + DP);
    dpTA[1] = (u16*)(arena + 9 * CB + 2 * DP); dpBA[1] = (u16*)(arena + 9 * CB + 3 * DP);
    gAll = (float*)(arena + 9 * CB + 4 * DP);
  } else {
    f1A[0] = f1A[1] = (u16*)arena;
    f2A[0] = f2A[1] = (u16*)(arena + CB);
    hhA[0] = (u16*)(arena + 2 * CB);
    hTA[0] = (u16*)(arena + 3 * CB);
    dzvT   = (u16*)(arena + 4 * CB);
    dpTA[0] = dpTA[1] = (u16*)(arena + 5 * CB);
    dpBA[0] = dpBA[1] = (u16*)(arena + 5 * CB + DP);
    gAll = (float*)(arena + 5 * CB + 2 * DP);
    hhA[1] = (MODE == 1) ? (u16*)(arena + 5 * CB + 2 * DP + 3 * PM * 4) : hhA[0];
    hTA[1] = (MODE == 1) ? (u16*)(arena + 6 * CB + 2 * DP + 3 * PM * 4) : hTA[0];
  }
  // P2 Newton-Schulz
  u16* XAb  = (u16*)arena;
  u16* XAbT = (u16*)(arena + 25165824);
  u16* Ab   = (u16*)(arena + 50331648);
  u16* Wb   = (u16*)(arena + 56623104);
  u16* Tb   = (u16*)(arena + 62914560);
  u16* Mb0  = (u16*)(arena + 69206016);
  u16* Mb1  = (u16*)(arena + 75497472);
  // P4 final forward
  u16* hbuf = (u16*)arena;
  u16* PWt  = (u16*)(arena + 92274688);

  const dim3 blk(256), tb32(32, 8);
  const float inv2 = 2.0f / (10992.0f * 1024.0f);
  const float nsa = 3.4445f, nsb = -4.7750f, nsc = 2.0315f;

  // ---- setup ----
  zero_tail<<<dim3(1024, 2), blk, 0, stream>>>(kT, vT);
  cvt_k<<<dim3(43968), blk, 0, stream>>>(x, xb, NTOK * 1024);
  tr_f32b<<<dim3(96, 32), tb32, 0, stream>>>(qkv_w, qkvWt, 3072, 1024);
  {  // fused: qkv+norm (y<86) || {Gt,Vt,Pt,projWt transposes + Pb cvt}
    GA a = mk(xb, qkvWt, qb, NTOK, 3072, 1024, 1024, 1024, 1024);
    a.O1[0] = kb; a.OT[0] = kT; a.OT[1] = vT;
    a.E0[0] = qkv_b; a.E0[1] = qn_s; a.E0[2] = kn_s;
    a.E1[0] = (const u16*)qn_b; a.E1[1] = (const u16*)kn_b;
    SP s{g_gate, g_val, g_proj, proj_w, Gt, Vt, Pt, projWt, Pb};
    setup_fused<<<dim3(24, 684, 1), blk, 0, stream>>>(a, s);
  }

  // ---- 2 TTT steps ----
  for (int step = 0; step < 2; ++step) {
    if (MODE != 2) hipMemsetAsync(gAll, 0, 3 * PM * 4, stream);
    if (MODE == 2) {
      const int NC = cdiv(NTOK, CHKr);
      int c0P = 0, vcP = 0, mtP = 0;
      for (int ci = 0; ci < NC; ++ci) {
        const int c0 = ci * CHKr;
        const int vc = (NTOK - c0 < CHKr) ? (NTOK - c0) : CHKr;
        const int mt = cdiv(vc, 128);
        const int par = ci & 1, parP = par ^ 1;
        const int tail = (ci == NC - 1 && vc < CHKr);
        if (tail) hipMemsetAsync(hTA[par], 0, CB, stream);
        // GV(ci) || DH(ci-1)
        GA agv{};
        agv.A[0] = kb + (size_t)c0 * 1024; agv.lda[0] = 1024;
        agv.B[0] = Gt; agv.B[1] = Vt; agv.ldb[0] = 1024;
        agv.C[0] = f1A[par]; agv.O1[0] = f2A[par]; agv.O1[1] = hhA[par]; agv.OT[0] = hTA[par];
        agv.M = vc; agv.N = 4096; agv.K = 1024; agv.ldc = 4096; agv.ldt = CHKr;
        if (ci == 0) {
          gemm_gv<0><<<dim3(32, mt, 1), blk, 0, stream>>>(agv);
        } else {
          GA adh{};
          adh.A[0] = dpBA[parP]; adh.B[0] = Pb; adh.lda[0] = 1024; adh.ldb[0] = 1024;
          adh.C[0] = hhA[parP]; adh.O1[0] = dzvT;
          adh.E0[0] = f1A[parP]; adh.E1[0] = f2A[parP];
          adh.M = vcP; adh.N = 4096; adh.K = 1024; adh.ldt = CHKr;
          adh.lde0 = 4096; adh.lde1 = 4096;
          fused_hg<<<dim3(32, mt + mtP, 1), blk, 0, stream>>>(adh, agv, mt);
        }
        // DPRED(ci) || GRADS(ci-1)
        if (tail) hipMemsetAsync(dpTA[par], 0, DP, stream);
        GA adp = mk(Pt, hhA[par], dpTA[par], 1024, vc, 4096, 4096, 4096, CHKr);
        adp.OT[0] = dpBA[par]; adp.ldt = 1024;
        adp.E0[0] = vT + c0; adp.lde0 = NTOKA; adp.p0 = inv2;
        const int dpx = cdiv(vc, 64);
        if (ci == 0) {
          gemm64<2><<<dim3(dpx, 16, 1), blk, 0, stream>>>(adp);
        } else {
          GA agr{};
          agr.A[0] = kT + c0P; agr.A[1] = kT + c0P; agr.A[2] = dpTA[parP];
          agr.lda[0] = NTOKA; agr.lda[1] = NTOKA; agr.lda[2] = CHKr;
          agr.B[0] = hhA[parP]; agr.B[1] = dzvT; agr.B[2] = hTA[parP];
          agr.ldb[0] = agr.ldb[1] = agr.ldb[2] = CHKr;
          agr.C[0] = gAll; agr.C[1] = gAll + PM; agr.C[2] = gAll + 2 * PM;
          agr.M = 1024; agr.N = 4096; agr.K = CHKr; agr.ldc = 4096;
          if (ci == 1)
            fused_gd<1><<<dim3(768 + dpx * 16, 1, 1), blk, 0, stream>>>(agr, adp, 768, dpx);
          else
            fused_gd<0><<<dim3(768 + dpx * 16, 1, 1), blk, 0, stream>>>(agr, adp, 768, dpx);
        }
        c0P = c0; vcP = vc; mtP = mt;
      }
      // epilogue: DH(last), GRADS(last, atomic split-K; K clamped to kT bounds)
      const int par = (NC - 1) & 1;
      if (vcP < CHKr) {
        hipMemsetAsync(hhA[par], 0, CB, stream);
        hipMemsetAsync(dzvT, 0, CB, stream);
      }
      {
        GA adh = mk(dpBA[par], Pb, hhA[par], vcP, 4096, 1024, 1024, 1024, 0);
        adh.O1[0] = dzvT; adh.ldt = CHKr;
        adh.E0[0] = f1A[par]; adh.lde0 = 4096; adh.E1[0] = f2A[par]; adh.lde1 = 4096;
        gemm_bt<5, 0><<<dim3(32, mtP, 1), blk, 0, stream>>>(adh);
      }
      {
        GA agr{};
        agr.A[0] = kT + c0P; agr.A[1] = kT + c0P; agr.A[2] = dpTA[par];
        agr.lda[0] = NTOKA; agr.lda[1] = NTOKA; agr.lda[2] = CHKr;
        agr.B[0] = hhA[par]; agr.B[1] = dzvT; agr.B[2] = hTA[par];
        agr.ldb[0] = agr.ldb[1] = agr.ldb[2] = CHKr;
        agr.C[0] = gAll; agr.C[1] = gAll + PM; agr.C[2] = gAll + 2 * PM;
        agr.M = 1024; agr.N = 4096; agr.K = mini(CHKr, NTOKA - c0P); agr.ldc = 4096;
        gemm_bt<8, 1><<<dim3(32, 8, 6), blk, 0, stream>>>(agr);
      }
    } else {
      // MODE <= 1 fallback loop
      int havePend = 0;
      GA pendGA{};
      for (int ci = 0, c0 = 0; c0 < NTOK; ++ci, c0 += CHKr) {
        const int vc = (NTOK - c0 < CHKr) ? (NTOK - c0) : CHKr;
        const int mt = cdiv(vc, 128);
        const u16* kc = kb + (size_t)c0 * 1024;
        u16* hhp = hhA[ci & 1];
        u16* hTp = hTA[ci & 1];
        if (vc < CHKr) hipMemsetAsync(hTp, 0, CB, stream);
        {
          GA agv{};
          agv.A[0] = kc; agv.lda[0] = 1024;
          agv.B[0] = Gt; agv.B[1] = Vt; agv.ldb[0] = 1024;
          agv.C[0] = f1A[0]; agv.O1[0] = f2A[0]; agv.O1[1] = hhp; agv.OT[0] = hTp;
          agv.M = vc; agv.N = 4096; agv.K = 1024; agv.ldc = 4096; agv.ldt = CHKr;
          if (MODE == 1 && havePend) {
            fused_gg<<<dim3(32, mt + 48, 1), blk, 0, stream>>>(pendGA, agv, mt);
            havePend = 0;
          } else {
            gemm_gv<0><<<dim3(32, mt, 1), blk, 0, stream>>>(agv);
          }
        }
        if (vc < CHKr) {
          hipMemsetAsync(dzvT, 0, CB, stream);
          hipMemsetAsync(dpTA[0], 0, DP, stream);
        }
        {
          GA a = mk(Pt, hhp, dpTA[0], 1024, vc, 4096, 4096, 4096, CHKr);
          a.OT[0] = dpBA[0]; a.ldt = 1024;
          a.E0[0] = vT + c0; a.lde0 = NTOKA; a.p0 = inv2;
          gemm64<2><<<dim3(cdiv(vc, 64), 16, 1), blk, 0, stream>>>(a);
        }
        if (vc < CHKr) hipMemsetAsync(hhp, 0, CB, stream);
        {
          GA a = mk(dpBA[0], Pb, hhp, vc, 4096, 1024, 1024, 1024, 0);
          a.O1[0] = dzvT; a.ldt = CHKr;
          a.E0[0] = f1A[0]; a.lde0 = 4096; a.E1[0] = f2A[0]; a.lde1 = 4096;
          gemm_bt<5, 0><<<dim3(32, mt, 1), blk, 0, stream>>>(a);
        }
        {
          GA a{};
          a.A[0] = kT + c0; a.A[1] = kT + c0; a.A[2] = dpTA[0];
          a.lda[0] = NTOKA; a.lda[1] = NTOKA; a.lda[2] = CHKr;
          a.B[0] = hhp; a.B[1] = dzvT; a.B[2] = hTp;
          a.ldb[0] = a.ldb[1] = a.ldb[2] = CHKr;
          a.C[0] = gAll; a.C[1] = gAll + PM; a.C[2] = gAll + 2 * PM;
          a.M = 1024; a.N = 4096; a.K = mini(CHKr, NTOKA - c0); a.ldc = 4096;
          const int last = (c0 + CHKr >= NTOK);
          if (MODE == 1 && !last) { pendGA = a; havePend = 1; }
          else gemm_bt<8, 1><<<dim3(32, 8, 6), blk, 0, stream>>>(a);
        }
      }
    }
    // X0 = g/||g||_F
    hipMemsetAsync(ssq, 0, 16, stream);
    sumsq_k<<<dim3(512, 3), blk, 0, stream>>>(gAll, ssq);
    scale_tr<<<dim3(128, 32, 3), tb32, 0, stream>>>(gAll, ssq, XAb, XAbT);

    // Newton-Schulz x5: Gram recursion + M^T product accumulation; apply fused (EPI 16)
    {  // A0 = X0@X0^T
      GA a{};
      for (int b = 0; b < 3; ++b) {
        a.A[b] = XAb + (size_t)b * PM; a.B[b] = XAb + (size_t)b * PM;
        a.C[b] = Ab + (size_t)b * 1048576;
        a.lda[b] = 4096; a.ldb[b] = 4096;
      }
      a.M = 1024; a.N = 1024; a.K = 4096; a.ldc = 1024;
      gemm64<10><<<dim3(16, 16, 3), blk, 0, stream>>>(a);
    }
    for (int it = 0; it < 5; ++it) {
      {  // W = nsb*A + nsc*A@A (sym); it0 also emits M0 = W + nsa*I (EPI13)
        GA a{};
        for (int b = 0; b < 3; ++b) {
          a.A[b] = Ab + (size_t)b * 1048576; a.B[b] = Ab + (size_t)b * 1048576;
          a.C[b] = Wb + (size_t)b * 1048576; a.E0[b] = Ab + (size_t)b * 1048576;
          a.OT[b] = Mb0 + (size_t)b * 1048576;
          a.lda[b] = 1024; a.ldb[b] = 1024;
        }
        a.M = 1024; a.N = 1024; a.K = 1024; a.ldc = 1024; a.lde0 = 1024;
        a.p0 = nsb; a.p1 = nsc;
        if (it == 0) gemm64<13><<<dim3(16, 16, 3), blk, 0, stream>>>(a);
        else gemm64<11><<<dim3(16, 16, 3), blk, 0, stream>>>(a);
      }
      if (it == 0) {
        {  // T = W@A
          GA a{};
          for (int b = 0; b < 3; ++b) {
            a.A[b] = Wb + (size_t)b * 1048576; a.B[b] = Ab + (size_t)b * 1048576;
            a.C[b] = Tb + (size_t)b * 1048576;
            a.lda[b] = 1024; a.ldb[b] = 1024;
          }
          a.M = 1024; a.N = 1024; a.K = 1024; a.ldc = 1024;
          gemm64<0><<<dim3(16, 16, 3), blk, 0, stream>>>(a);
        }
      } else if (it < 4) {
        u16* Mti = (it & 1) ? Mb0 : Mb1;
        u16* Mto = (it & 1) ? Mb1 : Mb0;
        GA gt{}, gm{};
        for (int b = 0; b < 3; ++b) {
          gt.A[b] = Wb + (size_t)b * 1048576; gt.B[b] = Ab + (size_t)b * 1048576;
          gt.C[b] = Tb + (size_t)b * 1048576;
          gt.lda[b] = 1024; gt.ldb[b] = 1024;
          gm.A[b] = Mti + (size_t)b * 1048576; gm.B[b] = Wb + (size_t)b * 1048576;
          gm.C[b] = Mto + (size_t)b * 1048576; gm.E0[b] = Mti + (size_t)b * 1048576;
          gm.lda[b] = 1024; gm.ldb[b] = 1024;
        }
        gt.M = gt.N = 1024; gt.K = 1024; gt.ldc = 1024;
        gm.M = gm.N = 1024; gm.K = 1024; gm.ldc = 1024; gm.lde0 = 1024; gm.p0 = nsa;
        fused_mt<<<dim3(16, 32, 3), blk, 0, stream>>>(gt, gm);
      } else {
        GA a{};
        for (int b = 0; b < 3; ++b) {
          a.A[b] = Wb + (size_t)b * 1048576; a.B[b] = Mb1 + (size_t)b * 1048576;
          a.C[b] = Mb0 + (size_t)b * 1048576; a.E0[b] = Mb1 + (size_t)b * 1048576;
          a.lda[b] = 1024; a.ldb[b] = 1024;
        }
        a.M = 1024; a.N = 1024; a.K = 1024; a.ldc = 1024; a.lde0 = 1024; a.p0 = nsa;
        gemm64<15><<<dim3(16, 16, 3), blk, 0, stream>>>(a);
      }
      if (it < 4) {  // A' = nsa^2*A + nsa*(T+T^T) + T@W
        GA a{};
        for (int b = 0; b < 3; ++b) {
          a.A[b] = Tb + (size_t)b * 1048576; a.B[b] = Wb + (size_t)b * 1048576;
          a.C[b] = Ab + (size_t)b * 1048576;
          a.E0[b] = Ab + (size_t)b * 1048576; a.E1[b] = Tb + (size_t)b * 1048576;
          a.lda[b] = 1024; a.ldb[b] = 1024;
        }
        a.M = 1024; a.N = 1024; a.K = 1024; a.ldc = 1024;
        a.lde0 = 1024; a.lde1 = 1024;
        a.p0 = nsa * nsa; a.p1 = nsa;
        gemm64<12><<<dim3(16, 16, 3), blk, 0, stream>>>(a);
      }
    }
    {  // fused apply: X5 = M4@X0; Muon RMW on Gt/Vt/Pb (+Pt scatter)
      GA a{};
      for (int b = 0; b < 3; ++b) {
        a.A[b] = Mb0 + (size_t)b * 1048576; a.B[b] = XAbT + (size_t)b * PM;
        a.lda[b] = 1024; a.ldb[b] = 1024;
      }
      a.C[0] = Gt; a.C[1] = Vt; a.C[2] = Pb;
      a.O1[0] = nullptr; a.O1[1] = nullptr; a.O1[2] = Pt;
      a.M = 1024; a.N = 4096; a.K = 1024; a.ldc = 1024;
      gemm_bt<16, 0><<<dim3(32, 8, 3), blk, 0, stream>>>(a);
    }
  }

  // ---- final: [h = swish(q@G)*q@V  ||  PWt = (P@projW)^T], then out = h@PWt + b ----
  {
    GA agv{};
    agv.A[0] = qb; agv.lda[0] = 1024;
    agv.B[0] = Gt; agv.B[1] = Vt; agv.ldb[0] = 1024;
    agv.C[0] = hbuf;
    agv.M = NTOK; agv.N = 4096; agv.K = 1024; agv.ldc = 4096;
    GA ap = mk(projWt, Pb, PWt, 1024, 4096, 1024, 1024, 1024, 4096);
    fused_pg<<<dim3(32, 94, 1), blk, 0, stream>>>(ap, agv, 86);
  }
  {
    GA a = mk(hbuf, PWt, out, NTOK, 1024, 4096, 4096, 4096, 1024);
    a.E0[0] = proj_b;
    gemm_bt<6, 0><<<dim3(8, 86, 1), blk, 0, stream>>>(a);
  }
}

// Round 8
// 5551.894 us; speedup vs baseline: 1.0174x; 1.0174x over previous
//
#include <hip/hip_runtime.h>
#include <stdint.h>

#define NTOK 10992      // B*SN
#define NTOKA 11264     // padded token dim
#define PMi 4194304

typedef unsigned short u16;
typedef __attribute__((ext_vector_type(8))) __bf16 b8;
typedef __attribute__((ext_vector_type(4))) float f32x4;

__device__ __forceinline__ u16 f2b(float f) {
  union { float f; uint32_t u; } v; v.f = f;
  return (u16)((v.u + 0x7fffu + ((v.u >> 16) & 1u)) >> 16);   // RNE
}
__device__ __forceinline__ float b2f(u16 b) {
  union { uint32_t u; float f; } v; v.u = ((uint32_t)b) << 16; return v.f;
}
__device__ __forceinline__ uint2 pk4(u16 a, u16 b, u16 c, u16 d) {
  uint2 r; r.x = (uint32_t)a | ((uint32_t)b << 16); r.y = (uint32_t)c | ((uint32_t)d << 16);
  return r;
}
__device__ __forceinline__ void gload16(const u16* g, u16* l) {
  __builtin_amdgcn_global_load_lds((const __attribute__((address_space(1))) void*)(const void*)g,
                                   (__attribute__((address_space(3))) void*)(void*)l, 16, 0, 0);
}

struct GA {
  const u16* A[3]; const u16* B[3];
  void* C[3]; u16* O1[3]; u16* OT[3];
  const void* E0[3]; const u16* E1[3];
  int lda[3], ldb[3];
  int M, N, K, ldc, ldo1, ldt, lde0, lde1;
  float p0, p1;
};

// ---------------- 128x128 tile GEMM: C[m,n] = sum_k A[m,k]*B[n,k] ----------------
// EPI: 0 Cb=acc | 5 dzg=acc*E0b->C(T-pack), dzv=acc*E1b->O1(T-pack)
//      6 Cf=acc+E0f[n] | 8 atomicAdd(Cf, acc)
//      16 Muon fused apply: Cb (X^T-layout) -= 0.1*acc via uint2 RMW; O1=Pt scatter
template <int EPI, int SPLIT>
__global__ __launch_bounds__(256, 2) void gemm_bt(GA g) {
  __shared__ u16 As[128 * 32];
  __shared__ u16 Bs[128 * 32];
  int bz = blockIdx.z, koff = 0, klen = g.K;
  if constexpr (SPLIT) { koff = (bz & 1) * (g.K >> 1); bz >>= 1; klen = g.K >> 1; }
  const u16* __restrict__ A = g.A[bz] + koff;
  const u16* __restrict__ B = g.B[bz] + koff;
  const int lda = g.lda[bz], ldb = g.ldb[bz];
  const int m0 = blockIdx.y * 128, n0 = blockIdx.x * 128;
  const int tid = threadIdx.x, w = tid >> 6, lane = tid & 63;
  const int wr = (w >> 1) * 64, wc = (w & 1) * 64;
  const int ln = lane & 15, lq = lane >> 4;

  f32x4 acc[4][4];
#pragma unroll
  for (int i = 0; i < 4; ++i)
#pragma unroll
    for (int j = 0; j < 4; ++j)
#pragma unroll
      for (int r = 0; r < 4; ++r) acc[i][j][r] = 0.f;

  const u16* Ag = A + (size_t)(m0 + 32 * w + (lane >> 2)) * lda + (lane & 3) * 8;
  const u16* Bg = B + (size_t)(n0 + 32 * w + (lane >> 2)) * ldb + (lane & 3) * 8;
  u16* AsW = &As[w * 1024];
  u16* BsW = &Bs[w * 1024];
  const int nkt = klen >> 5;

  for (int kt = 0; kt < nkt; ++kt) {
    __syncthreads();
    gload16(Ag, AsW);
    gload16(Ag + (size_t)16 * lda, AsW + 512);
    gload16(Bg, BsW);
    gload16(Bg + (size_t)16 * ldb, BsW + 512);
    Ag += 32; Bg += 32;
    __syncthreads();
    b8 af[4], bfr[4];
#pragma unroll
    for (int i = 0; i < 4; ++i) af[i] = *(const b8*)&As[(wr + i * 16 + ln) * 32 + lq * 8];
#pragma unroll
    for (int j = 0; j < 4; ++j) bfr[j] = *(const b8*)&Bs[(wc + j * 16 + ln) * 32 + lq * 8];
#pragma unroll
    for (int i = 0; i < 4; ++i)
#pragma unroll
      for (int j = 0; j < 4; ++j)
        acc[i][j] = __builtin_amdgcn_mfma_f32_16x16x32_bf16(af[i], bfr[j], acc[i][j], 0, 0, 0);
  }

  float* Cf = (float*)g.C[bz];
  u16* Cb = (u16*)g.C[bz];
  u16* O1 = g.O1[bz];
  const float* E0f = (const float*)g.E0[bz];
  const u16* E0b = (const u16*)g.E0[bz];
  const u16* E1b = g.E1[bz];

#pragma unroll
  for (int i = 0; i < 4; ++i) {
    const int mb = m0 + wr + i * 16 + lq * 4;
    if (mb >= g.M) continue;
#pragma unroll
    for (int j = 0; j < 4; ++j) {
      const int n = n0 + wc + j * 16 + ln;
      if (n >= g.N) continue;
      float vv[4];
#pragma unroll
      for (int r = 0; r < 4; ++r) vv[r] = acc[i][j][r];
      if constexpr (EPI == 0) {
#pragma unroll
        for (int r = 0; r < 4; ++r) Cb[(size_t)(mb + r) * g.ldc + n] = f2b(vv[r]);
      } else if constexpr (EPI == 5) {
        u16 cq[4], oq[4];
#pragma unroll
        for (int r = 0; r < 4; ++r) {
          const int m = mb + r;
          const float f1 = b2f(E0b[(size_t)m * g.lde0 + n]);
          const float f2 = b2f(E1b[(size_t)m * g.lde1 + n]);
          cq[r] = f2b(vv[r] * f1);
          oq[r] = f2b(vv[r] * f2);
        }
        *(uint2*)&Cb[(size_t)n * g.ldt + mb] = pk4(cq[0], cq[1], cq[2], cq[3]);
        *(uint2*)&O1[(size_t)n * g.ldt + mb] = pk4(oq[0], oq[1], oq[2], oq[3]);
      } else if constexpr (EPI == 6) {
        const float bias = E0f[n];
#pragma unroll
        for (int r = 0; r < 4; ++r) Cf[(size_t)(mb + r) * g.ldc + n] = vv[r] + bias;
      } else if constexpr (EPI == 8) {
#pragma unroll
        for (int r = 0; r < 4; ++r) atomicAdd(&Cf[(size_t)(mb + r) * g.ldc + n], vv[r]);
      } else if constexpr (EPI == 16) {
        uint2 old = *(const uint2*)&Cb[(size_t)n * 1024 + mb];
        u16 nq[4];
        nq[0] = f2b(b2f((u16)(old.x & 0xffff)) - 0.1f * vv[0]);
        nq[1] = f2b(b2f((u16)(old.x >> 16)) - 0.1f * vv[1]);
        nq[2] = f2b(b2f((u16)(old.y & 0xffff)) - 0.1f * vv[2]);
        nq[3] = f2b(b2f((u16)(old.y >> 16)) - 0.1f * vv[3]);
        *(uint2*)&Cb[(size_t)n * 1024 + mb] = pk4(nq[0], nq[1], nq[2], nq[3]);
        if (O1) {
#pragma unroll
          for (int r = 0; r < 4; ++r) O1[(size_t)(mb + r) * 4096 + n] = nq[r];
        }
      }
    }
  }
}

// ---------------- fused qkv GEMM + head-L2-norm ----------------
// C[m,n] = x@qkvW^T + bias; per-64-col head L2 norm for q/k segments.
// Writes: qb (rows), kb (rows) + kT (T-pack), vT (T-pack only).
// E0[0]=qkv_b(f32) E0[1]=qn_s E0[2]=kn_s E1[0]=qn_b E1[1]=kn_b
__global__ __launch_bounds__(256, 2) void gemm_qkv(GA g) {
  __shared__ u16 As[128 * 32];
  __shared__ u16 Bs[128 * 32];
  const u16* __restrict__ A = g.A[0];
  const u16* __restrict__ B = g.B[0];
  const int lda = g.lda[0], ldb = g.ldb[0];
  const int m0 = blockIdx.y * 128, n0 = blockIdx.x * 128;
  const int tid = threadIdx.x, w = tid >> 6, lane = tid & 63;
  const int wr = (w >> 1) * 64, wc = (w & 1) * 64;
  const int ln = lane & 15, lq = lane >> 4;

  f32x4 acc[4][4];
#pragma unroll
  for (int i = 0; i < 4; ++i)
#pragma unroll
    for (int j = 0; j < 4; ++j)
#pragma unroll
      for (int r = 0; r < 4; ++r) acc[i][j][r] = 0.f;

  const u16* Ag = A + (size_t)(m0 + 32 * w + (lane >> 2)) * lda + (lane & 3) * 8;
  const u16* Bg = B + (size_t)(n0 + 32 * w + (lane >> 2)) * ldb + (lane & 3) * 8;
  u16* AsW = &As[w * 1024];
  u16* BsW = &Bs[w * 1024];
  const int nkt = g.K >> 5;

  for (int kt = 0; kt < nkt; ++kt) {
    __syncthreads();
    gload16(Ag, AsW);
    gload16(Ag + (size_t)16 * lda, AsW + 512);
    gload16(Bg, BsW);
    gload16(Bg + (size_t)16 * ldb, BsW + 512);
    Ag += 32; Bg += 32;
    __syncthreads();
    b8 af[4], bfr[4];
#pragma unroll
    for (int i = 0; i < 4; ++i) af[i] = *(const b8*)&As[(wr + i * 16 + ln) * 32 + lq * 8];
#pragma unroll
    for (int j = 0; j < 4; ++j) bfr[j] = *(const b8*)&Bs[(wc + j * 16 + ln) * 32 + lq * 8];
#pragma unroll
    for (int i = 0; i < 4; ++i)
#pragma unroll
      for (int j = 0; j < 4; ++j)
        acc[i][j] = __builtin_amdgcn_mfma_f32_16x16x32_bf16(af[i], bfr[j], acc[i][j], 0, 0, 0);
  }

  u16* qbp = (u16*)g.C[0];
  u16* kbp = g.O1[0];
  u16* kTp = g.OT[0];
  u16* vTp = g.OT[1];
  const float* bias = (const float*)g.E0[0];
  const float* qS = (const float*)g.E0[1];
  const float* kS = (const float*)g.E0[2];
  const float* qB = (const float*)g.E1[0];
  const float* kB = (const float*)g.E1[1];
  const int seg = (n0 + wc) >> 10;   // 0=q, 1=k, 2=v (warp-uniform: 64-col head within one seg)

#pragma unroll
  for (int i = 0; i < 4; ++i) {
    const int mb = m0 + wr + i * 16 + lq * 4;
    if (mb >= g.M) continue;
    float vb4[4][4];
    float s4[4] = {0.f, 0.f, 0.f, 0.f};
#pragma unroll
    for (int j = 0; j < 4; ++j) {
      const int n = n0 + wc + j * 16 + ln;
      const float bs = bias[n];
#pragma unroll
      for (int r = 0; r < 4; ++r) {
        const float v = acc[i][j][r] + bs;
        vb4[j][r] = v;
        s4[r] += v * v;
      }
    }
    if (seg == 2) {
#pragma unroll
      for (int j = 0; j < 4; ++j) {
        const int n = n0 + wc + j * 16 + ln;
        *(uint2*)&vTp[(size_t)(n - 2048) * NTOKA + mb] =
            pk4(f2b(vb4[j][0]), f2b(vb4[j][1]), f2b(vb4[j][2]), f2b(vb4[j][3]));
      }
    } else {
      // reduce across the 16 ln-lanes (one head = j(4) x ln(16) = 64 cols)
#pragma unroll
      for (int off = 1; off < 16; off <<= 1)
#pragma unroll
        for (int r = 0; r < 4; ++r) s4[r] += __shfl_xor(s4[r], off);
      float rinv[4];
#pragma unroll
      for (int r = 0; r < 4; ++r) rinv[r] = 1.f / (sqrtf(s4[r]) + 1e-6f);
      if (seg == 0) {
#pragma unroll
        for (int j = 0; j < 4; ++j) {
          const int n = n0 + wc + j * 16 + ln;
          const int hd = n & 63;
          const float sc = qS[hd], bi = qB[hd];
#pragma unroll
          for (int r = 0; r < 4; ++r)
            qbp[(size_t)(mb + r) * 1024 + n] = f2b(vb4[j][r] * rinv[r] * sc + bi);
        }
      } else {
#pragma unroll
        for (int j = 0; j < 4; ++j) {
          const int n = n0 + wc + j * 16 + ln;
          const int hd = n & 63;
          const float sc = kS[hd], bi = kB[hd];
          u16 kq[4];
#pragma unroll
          for (int r = 0; r < 4; ++r) {
            kq[r] = f2b(vb4[j][r] * rinv[r] * sc + bi);
            kbp[(size_t)(mb + r) * 1024 + (n - 1024)] = kq[r];
          }
          *(uint2*)&kTp[(size_t)(n - 1024) * NTOKA + mb] = pk4(kq[0], kq[1], kq[2], kq[3]);
        }
      }
    }
  }
}

// ---------------- fused dual-B GEMM: zg=A@G^T, zv=A@V^T ----------------
// EPI 0 (chunk loop): store f1=zv*s*(1+zg(1-s)) (C), f2=zg*s (O1[0]), h (O1[1]), hT (OT[0])
// EPI 1 (final fwd):  store h only (C)
template <int EPI>
__global__ __launch_bounds__(256, 2) void gemm_gv(GA g) {
  __shared__ u16 As[128 * 32];
  __shared__ u16 Gs[128 * 32];
  __shared__ u16 Vs[128 * 32];
  const u16* __restrict__ A = g.A[0];
  const u16* __restrict__ G = g.B[0];
  const u16* __restrict__ V = g.B[1];
  const int lda = g.lda[0], ldb = g.ldb[0];
  const int m0 = blockIdx.y * 128, n0 = blockIdx.x * 128;
  const int tid = threadIdx.x, w = tid >> 6, lane = tid & 63;
  const int wr = (w >> 1) * 64, wc = (w & 1) * 64;
  const int ln = lane & 15, lq = lane >> 4;

  f32x4 ag[4][4], av[4][4];
#pragma unroll
  for (int i = 0; i < 4; ++i)
#pragma unroll
    for (int j = 0; j < 4; ++j)
#pragma unroll
      for (int r = 0; r < 4; ++r) { ag[i][j][r] = 0.f; av[i][j][r] = 0.f; }

  const u16* Agp = A + (size_t)(m0 + 32 * w + (lane >> 2)) * lda + (lane & 3) * 8;
  const u16* Ggp = G + (size_t)(n0 + 32 * w + (lane >> 2)) * ldb + (lane & 3) * 8;
  const u16* Vgp = V + (size_t)(n0 + 32 * w + (lane >> 2)) * ldb + (lane & 3) * 8;
  u16* AsW = &As[w * 1024];
  u16* GsW = &Gs[w * 1024];
  u16* VsW = &Vs[w * 1024];
  const int nkt = g.K >> 5;

  for (int kt = 0; kt < nkt; ++kt) {
    __syncthreads();
    gload16(Agp, AsW);
    gload16(Agp + (size_t)16 * lda, AsW + 512);
    gload16(Ggp, GsW);
    gload16(Ggp + (size_t)16 * ldb, GsW + 512);
    gload16(Vgp, VsW);
    gload16(Vgp + (size_t)16 * ldb, VsW + 512);
    Agp += 32; Ggp += 32; Vgp += 32;
    __syncthreads();
    b8 af[4], gf[4], vf[4];
#pragma unroll
    for (int i = 0; i < 4; ++i) af[i] = *(const b8*)&As[(wr + i * 16 + ln) * 32 + lq * 8];
#pragma unroll
    for (int j = 0; j < 4; ++j) gf[j] = *(const b8*)&Gs[(wc + j * 16 + ln) * 32 + lq * 8];
#pragma unroll
    for (int j = 0; j < 4; ++j) vf[j] = *(const b8*)&Vs[(wc + j * 16 + ln) * 32 + lq * 8];
#pragma unroll
    for (int i = 0; i < 4; ++i)
#pragma unroll
      for (int j = 0; j < 4; ++j) {
        ag[i][j] = __builtin_amdgcn_mfma_f32_16x16x32_bf16(af[i], gf[j], ag[i][j], 0, 0, 0);
        av[i][j] = __builtin_amdgcn_mfma_f32_16x16x32_bf16(af[i], vf[j], av[i][j], 0, 0, 0);
      }
  }

  u16* F1 = (u16*)g.C[0];
  u16* F2 = g.O1[0];
  u16* Hh = g.O1[1];
  u16* HT = g.OT[0];

#pragma unroll
  for (int i = 0; i < 4; ++i) {
    const int mb = m0 + wr + i * 16 + lq * 4;
    if (mb >= g.M) continue;
#pragma unroll
    for (int j = 0; j < 4; ++j) {
      const int n = n0 + wc + j * 16 + ln;
      if (n >= g.N) continue;
      u16 hq[4];
#pragma unroll
      for (int r = 0; r < 4; ++r) {
        const int m = mb + r;
        const float zg = ag[i][j][r];
        const float zv = av[i][j][r];
        const float s = 1.f / (1.f + __expf(-zg));
        const float sw = zg * s;
        if constexpr (EPI == 0) {
          F1[(size_t)m * g.ldc + n] = f2b(zv * s * (1.f + zg * (1.f - s)));
          F2[(size_t)m * g.ldc + n] = f2b(sw);
          const u16 hb = f2b(sw * zv);
          Hh[(size_t)m * g.ldc + n] = hb;
          hq[r] = hb;
        } else {
          F1[(size_t)m * g.ldc + n] = f2b(sw * zv);
        }
      }
      if constexpr (EPI == 0)
        *(uint2*)&HT[(size_t)n * g.ldt + mb] = pk4(hq[0], hq[1], hq[2], hq[3]);
    }
  }
}

// ---------------- fused pair: gv(c+1) + grads(c) (MODE 1 fallback) ----------------
__global__ __launch_bounds__(256, 2) void fused_gg(GA ggr, GA ggv, int ysplit) {
  __shared__ u16 As[128 * 32];
  __shared__ u16 Bs[128 * 32];
  __shared__ u16 Vs[128 * 32];
  const int tid = threadIdx.x, w = tid >> 6, lane = tid & 63;
  const int wr = (w >> 1) * 64, wc = (w & 1) * 64;
  const int ln = lane & 15, lq = lane >> 4;

  if ((int)blockIdx.y < ysplit) {
    const u16* __restrict__ A = ggv.A[0];
    const u16* __restrict__ G = ggv.B[0];
    const u16* __restrict__ V = ggv.B[1];
    const int lda = ggv.lda[0], ldb = ggv.ldb[0];
    const int m0 = blockIdx.y * 128, n0 = blockIdx.x * 128;
    f32x4 ag[4][4], av[4][4];
#pragma unroll
    for (int i = 0; i < 4; ++i)
#pragma unroll
      for (int j = 0; j < 4; ++j)
#pragma unroll
        for (int r = 0; r < 4; ++r) { ag[i][j][r] = 0.f; av[i][j][r] = 0.f; }
    const u16* Agp = A + (size_t)(m0 + 32 * w + (lane >> 2)) * lda + (lane & 3) * 8;
    const u16* Ggp = G + (size_t)(n0 + 32 * w + (lane >> 2)) * ldb + (lane & 3) * 8;
    const u16* Vgp = V + (size_t)(n0 + 32 * w + (lane >> 2)) * ldb + (lane & 3) * 8;
    u16* AsW = &As[w * 1024];
    u16* GsW = &Bs[w * 1024];
    u16* VsW = &Vs[w * 1024];
    const int nkt = ggv.K >> 5;
    for (int kt = 0; kt < nkt; ++kt) {
      __syncthreads();
      gload16(Agp, AsW);
      gload16(Agp + (size_t)16 * lda, AsW + 512);
      gload16(Ggp, GsW);
      gload16(Ggp + (size_t)16 * ldb, GsW + 512);
      gload16(Vgp, VsW);
      gload16(Vgp + (size_t)16 * ldb, VsW + 512);
      Agp += 32; Ggp += 32; Vgp += 32;
      __syncthreads();
      b8 af[4], gf[4], vf[4];
#pragma unroll
      for (int i = 0; i < 4; ++i) af[i] = *(const b8*)&As[(wr + i * 16 + ln) * 32 + lq * 8];
#pragma unroll
      for (int j = 0; j < 4; ++j) gf[j] = *(const b8*)&Bs[(wc + j * 16 + ln) * 32 + lq * 8];
#pragma unroll
      for (int j = 0; j < 4; ++j) vf[j] = *(const b8*)&Vs[(wc + j * 16 + ln) * 32 + lq * 8];
#pragma unroll
      for (int i = 0; i < 4; ++i)
#pragma unroll
        for (int j = 0; j < 4; ++j) {
          ag[i][j] = __builtin_amdgcn_mfma_f32_16x16x32_bf16(af[i], gf[j], ag[i][j], 0, 0, 0);
          av[i][j] = __builtin_amdgcn_mfma_f32_16x16x32_bf16(af[i], vf[j], av[i][j], 0, 0, 0);
        }
    }
    u16* F1 = (u16*)ggv.C[0];
    u16* F2 = ggv.O1[0];
    u16* Hh = ggv.O1[1];
    u16* HT = ggv.OT[0];
#pragma unroll
    for (int i = 0; i < 4; ++i) {
      const int mb = m0 + wr + i * 16 + lq * 4;
      if (mb >= ggv.M) continue;
#pragma unroll
      for (int j = 0; j < 4; ++j) {
        const int n = n0 + wc + j * 16 + ln;
        if (n >= ggv.N) continue;
        u16 hq[4];
#pragma unroll
        for (int r = 0; r < 4; ++r) {
          const int m = mb + r;
          const float zg = ag[i][j][r];
          const float zv = av[i][j][r];
          const float s = 1.f / (1.f + __expf(-zg));
          const float sw = zg * s;
          F1[(size_t)m * ggv.ldc + n] = f2b(zv * s * (1.f + zg * (1.f - s)));
          F2[(size_t)m * ggv.ldc + n] = f2b(sw);
          const u16 hb = f2b(sw * zv);
          Hh[(size_t)m * ggv.ldc + n] = hb;
          hq[r] = hb;
        }
        *(uint2*)&HT[(size_t)n * ggv.ldt + mb] = pk4(hq[0], hq[1], hq[2], hq[3]);
      }
    }
  } else {
    const int yy = (int)blockIdx.y - ysplit;       // [0, 48)
    int bz = yy >> 3;
    const int m0 = (yy & 7) * 128, n0 = blockIdx.x * 128;
    const int koff = (bz & 1) * (ggr.K >> 1); bz >>= 1;
    const int klen = ggr.K >> 1;
    const u16* __restrict__ A = ggr.A[bz] + koff;
    const u16* __restrict__ B = ggr.B[bz] + koff;
    const int lda = ggr.lda[bz], ldb = ggr.ldb[bz];
    f32x4 acc[4][4];
#pragma unroll
    for (int i = 0; i < 4; ++i)
#pragma unroll
      for (int j = 0; j < 4; ++j)
#pragma unroll
        for (int r = 0; r < 4; ++r) acc[i][j][r] = 0.f;
    const u16* Ag = A + (size_t)(m0 + 32 * w + (lane >> 2)) * lda + (lane & 3) * 8;
    const u16* Bg = B + (size_t)(n0 + 32 * w + (lane >> 2)) * ldb + (lane & 3) * 8;
    u16* AsW = &As[w * 1024];
    u16* BsW = &Bs[w * 1024];
    const int nkt = klen >> 5;
    for (int kt = 0; kt < nkt; ++kt) {
      __syncthreads();
      gload16(Ag, AsW);
      gload16(Ag + (size_t)16 * lda, AsW + 512);
      gload16(Bg, BsW);
      gload16(Bg + (size_t)16 * ldb, BsW + 512);
      Ag += 32; Bg += 32;
      __syncthreads();
      b8 af[4], bfr[4];
#pragma unroll
      for (int i = 0; i < 4; ++i) af[i] = *(const b8*)&As[(wr + i * 16 + ln) * 32 + lq * 8];
#pragma unroll
      for (int j = 0; j < 4; ++j) bfr[j] = *(const b8*)&Bs[(wc + j * 16 + ln) * 32 + lq * 8];
#pragma unroll
      for (int i = 0; i < 4; ++i)
#pragma unroll
        for (int j = 0; j < 4; ++j)
          acc[i][j] = __builtin_amdgcn_mfma_f32_16x16x32_bf16(af[i], bfr[j], acc[i][j], 0, 0, 0);
    }
    float* Cf = (float*)ggr.C[bz];
#pragma unroll
    for (int i = 0; i < 4; ++i) {
      const int mb = m0 + wr + i * 16 + lq * 4;
      if (mb >= ggr.M) continue;
#pragma unroll
      for (int j = 0; j < 4; ++j) {
        const int n = n0 + wc + j * 16 + ln;
        if (n >= ggr.N) continue;
#pragma unroll
        for (int r = 0; r < 4; ++r) atomicAdd(&Cf[(size_t)(mb + r) * ggr.ldc + n], acc[i][j][r]);
      }
    }
  }
}

// ---------------- fused pair: gv(ci) (y<ysplit) || dh(ci-1) (y>=ysplit) ----------------
__global__ __launch_bounds__(256, 2) void fused_hg(GA gdh, GA ggv, int ysplit) {
  __shared__ u16 As[128 * 32];
  __shared__ u16 Bs[128 * 32];
  __shared__ u16 Vs[128 * 32];
  const int tid = threadIdx.x, w = tid >> 6, lane = tid & 63;
  const int wr = (w >> 1) * 64, wc = (w & 1) * 64;
  const int ln = lane & 15, lq = lane >> 4;

  if ((int)blockIdx.y < ysplit) {
    // ---------- gv path ----------
    const u16* __restrict__ A = ggv.A[0];
    const u16* __restrict__ G = ggv.B[0];
    const u16* __restrict__ V = ggv.B[1];
    const int lda = ggv.lda[0], ldb = ggv.ldb[0];
    const int m0 = blockIdx.y * 128, n0 = blockIdx.x * 128;
    f32x4 ag[4][4], av[4][4];
#pragma unroll
    for (int i = 0; i < 4; ++i)
#pragma unroll
      for (int j = 0; j < 4; ++j)
#pragma unroll
        for (int r = 0; r < 4; ++r) { ag[i][j][r] = 0.f; av[i][j][r] = 0.f; }
    const u16* Agp = A + (size_t)(m0 + 32 * w + (lane >> 2)) * lda + (lane & 3) * 8;
    const u16* Ggp = G + (size_t)(n0 + 32 * w + (lane >> 2)) * ldb + (lane & 3) * 8;
    const u16* Vgp = V + (size_t)(n0 + 32 * w + (lane >> 2)) * ldb + (lane & 3) * 8;
    u16* AsW = &As[w * 1024];
    u16* GsW = &Bs[w * 1024];
    u16* VsW = &Vs[w * 1024];
    const int nkt = ggv.K >> 5;
    for (int kt = 0; kt < nkt; ++kt) {
      __syncthreads();
      gload16(Agp, AsW);
      gload16(Agp + (size_t)16 * lda, AsW + 512);
      gload16(Ggp, GsW);
      gload16(Ggp + (size_t)16 * ldb, GsW + 512);
      gload16(Vgp, VsW);
      gload16(Vgp + (size_t)16 * ldb, VsW + 512);
      Agp += 32; Ggp += 32; Vgp += 32;
      __syncthreads();
      b8 af[4], gf[4], vf[4];
#pragma unroll
      for (int i = 0; i < 4; ++i) af[i] = *(const b8*)&As[(wr + i * 16 + ln) * 32 + lq * 8];
#pragma unroll
      for (int j = 0; j < 4; ++j) gf[j] = *(const b8*)&Bs[(wc + j * 16 + ln) * 32 + lq * 8];
#pragma unroll
      for (int j = 0; j < 4; ++j) vf[j] = *(const b8*)&Vs[(wc + j * 16 + ln) * 32 + lq * 8];
#pragma unroll
      for (int i = 0; i < 4; ++i)
#pragma unroll
        for (int j = 0; j < 4; ++j) {
          ag[i][j] = __builtin_amdgcn_mfma_f32_16x16x32_bf16(af[i], gf[j], ag[i][j], 0, 0, 0);
          av[i][j] = __builtin_amdgcn_mfma_f32_16x16x32_bf16(af[i], vf[j], av[i][j], 0, 0, 0);
        }
    }
    u16* F1 = (u16*)ggv.C[0];
    u16* F2 = ggv.O1[0];
    u16* Hh = ggv.O1[1];
    u16* HT = ggv.OT[0];
#pragma unroll
    for (int i = 0; i < 4; ++i) {
      const int mb = m0 + wr + i * 16 + lq * 4;
      if (mb >= ggv.M) continue;
#pragma unroll
      for (int j = 0; j < 4; ++j) {
        const int n = n0 + wc + j * 16 + ln;
        u16 hq[4];
#pragma unroll
        for (int r = 0; r < 4; ++r) {
          const int m = mb + r;
          const float zg = ag[i][j][r];
          const float zv = av[i][j][r];
          const float s = 1.f / (1.f + __expf(-zg));
          const float sw = zg * s;
          F1[(size_t)m * ggv.ldc + n] = f2b(zv * s * (1.f + zg * (1.f - s)));
          F2[(size_t)m * ggv.ldc + n] = f2b(sw);
          const u16 hb = f2b(sw * zv);
          Hh[(size_t)m * ggv.ldc + n] = hb;
          hq[r] = hb;
        }
        *(uint2*)&HT[(size_t)n * ggv.ldt + mb] = pk4(hq[0], hq[1], hq[2], hq[3]);
      }
    }
  } else {
    // ---------- dh path ----------
    const int m0 = ((int)blockIdx.y - ysplit) * 128, n0 = blockIdx.x * 128;
    const u16* __restrict__ A = gdh.A[0];
    const u16* __restrict__ B = gdh.B[0];
    const int lda = gdh.lda[0], ldb = gdh.ldb[0];
    f32x4 acc[4][4];
#pragma unroll
    for (int i = 0; i < 4; ++i)
#pragma unroll
      for (int j = 0; j < 4; ++j)
#pragma unroll
        for (int r = 0; r < 4; ++r) acc[i][j][r] = 0.f;
    const u16* Ag = A + (size_t)(m0 + 32 * w + (lane >> 2)) * lda + (lane & 3) * 8;
    const u16* Bg = B + (size_t)(n0 + 32 * w + (lane >> 2)) * ldb + (lane & 3) * 8;
    u16* AsW = &As[w * 1024];
    u16* BsW = &Bs[w * 1024];
    const int nkt = gdh.K >> 5;
    for (int kt = 0; kt < nkt; ++kt) {
      __syncthreads();
      gload16(Ag, AsW);
      gload16(Ag + (size_t)16 * lda, AsW + 512);
      gload16(Bg, BsW);
      gload16(Bg + (size_t)16 * ldb, BsW + 512);
      Ag += 32; Bg += 32;
      __syncthreads();
      b8 af[4], bfr[4];
#pragma unroll
      for (int i = 0; i < 4; ++i) af[i] = *(const b8*)&As[(wr + i * 16 + ln) * 32 + lq * 8];
#pragma unroll
      for (int j = 0; j < 4; ++j) bfr[j] = *(const b8*)&Bs[(wc + j * 16 + ln) * 32 + lq * 8];
#pragma unroll
      for (int i = 0; i < 4; ++i)
#pragma unroll
        for (int j = 0; j < 4; ++j)
          acc[i][j] = __builtin_amdgcn_mfma_f32_16x16x32_bf16(af[i], bfr[j], acc[i][j], 0, 0, 0);
    }
    u16* Cb = (u16*)gdh.C[0];
    u16* O1 = gdh.O1[0];
    const u16* E0b = (const u16*)gdh.E0[0];
    const u16* E1b = gdh.E1[0];
#pragma unroll
    for (int i = 0; i < 4; ++i) {
      const int mb = m0 + wr + i * 16 + lq * 4;
      if (mb >= gdh.M) continue;
#pragma unroll
      for (int j = 0; j < 4; ++j) {
        const int n = n0 + wc + j * 16 + ln;
        u16 cq[4], oq[4];
#pragma unroll
        for (int r = 0; r < 4; ++r) {
          const int m = mb + r;
          const float f1 = b2f(E0b[(size_t)m * gdh.lde0 + n]);
          const float f2 = b2f(E1b[(size_t)m * gdh.lde1 + n]);
          cq[r] = f2b(acc[i][j][r] * f1);
          oq[r] = f2b(acc[i][j][r] * f2);
        }
        *(uint2*)&Cb[(size_t)n * gdh.ldt + mb] = pk4(cq[0], cq[1], cq[2], cq[3]);
        *(uint2*)&O1[(size_t)n * gdh.ldt + mb] = pk4(oq[0], oq[1], oq[2], oq[3]);
      }
    }
  }
}

// ---------------- fused pair: grads(ci-1) [bid<nGr, split-K=2 atomic] || dpred(ci) [rest] ----------------
__global__ __launch_bounds__(256, 2) void fused_gd(GA ggr, GA gdp, int nGr, int dpx) {
  __shared__ u16 As[128 * 32];
  __shared__ u16 Bs[128 * 32];
  const int tid = threadIdx.x, w = tid >> 6, lane = tid & 63;
  const int ln = lane & 15, lq = lane >> 4;
  const int bid = blockIdx.x;

  if (bid < nGr) {
    // grads path (gemm_bt<8,1> body); nGr = 32*8*6 = 1536
    const int wr = (w >> 1) * 64, wc = (w & 1) * 64;
    const int n0 = (bid & 31) * 128;
    const int rest = bid >> 5;                // [0,48)
    const int m0 = (rest & 7) * 128;
    int bz = rest >> 3;                       // [0,6)
    const int koff = (bz & 1) * (ggr.K >> 1); bz >>= 1;
    const int klen = ggr.K >> 1;
    const u16* __restrict__ A = ggr.A[bz] + koff;
    const u16* __restrict__ B = ggr.B[bz] + koff;
    const int lda = ggr.lda[bz], ldb = ggr.ldb[bz];
    f32x4 acc[4][4];
#pragma unroll
    for (int i = 0; i < 4; ++i)
#pragma unroll
      for (int j = 0; j < 4; ++j)
#pragma unroll
        for (int r = 0; r < 4; ++r) acc[i][j][r] = 0.f;
    const u16* Ag = A + (size_t)(m0 + 32 * w + (lane >> 2)) * lda + (lane & 3) * 8;
    const u16* Bg = B + (size_t)(n0 + 32 * w + (lane >> 2)) * ldb + (lane & 3) * 8;
    u16* AsW = &As[w * 1024];
    u16* BsW = &Bs[w * 1024];
    const int nkt = klen >> 5;
    for (int kt = 0; kt < nkt; ++kt) {
      __syncthreads();
      gload16(Ag, AsW);
      gload16(Ag + (size_t)16 * lda, AsW + 512);
      gload16(Bg, BsW);
      gload16(Bg + (size_t)16 * ldb, BsW + 512);
      Ag += 32; Bg += 32;
      __syncthreads();
      b8 af[4], bfr[4];
#pragma unroll
      for (int i = 0; i < 4; ++i) af[i] = *(const b8*)&As[(wr + i * 16 + ln) * 32 + lq * 8];
#pragma unroll
      for (int j = 0; j < 4; ++j) bfr[j] = *(const b8*)&Bs[(wc + j * 16 + ln) * 32 + lq * 8];
#pragma unroll
      for (int i = 0; i < 4; ++i)
#pragma unroll
        for (int j = 0; j < 4; ++j)
          acc[i][j] = __builtin_amdgcn_mfma_f32_16x16x32_bf16(af[i], bfr[j], acc[i][j], 0, 0, 0);
    }
    float* Cf = (float*)ggr.C[bz];
#pragma unroll
    for (int i = 0; i < 4; ++i) {
      const int mb = m0 + wr + i * 16 + lq * 4;
#pragma unroll
      for (int j = 0; j < 4; ++j) {
        const int n = n0 + wc + j * 16 + ln;
#pragma unroll
        for (int r = 0; r < 4; ++r) atomicAdd(&Cf[(size_t)(mb + r) * ggr.ldc + n], acc[i][j][r]);
      }
    }
  } else {
    // dpred path (gemm64<2> body)
    const int wr = (w >> 1) * 32, wc = (w & 1) * 32;
    const int l = bid - nGr;
    const int n0 = (l % dpx) * 64;
    const int m0 = (l / dpx) * 64;
    const u16* __restrict__ A = gdp.A[0];
    const u16* __restrict__ B = gdp.B[0];
    const int lda = gdp.lda[0], ldb = gdp.ldb[0];
    f32x4 acc[2][2];
#pragma unroll
    for (int i = 0; i < 2; ++i)
#pragma unroll
      for (int j = 0; j < 2; ++j)
#pragma unroll
        for (int r = 0; r < 4; ++r) acc[i][j][r] = 0.f;
    const u16* Ag = A + (size_t)(m0 + 16 * w + (lane >> 2)) * lda + (lane & 3) * 8;
    const u16* Bg = B + (size_t)(n0 + 16 * w + (lane >> 2)) * ldb + (lane & 3) * 8;
    u16* AsW = &As[w * 512];
    u16* BsW = &Bs[w * 512];
    const int nkt = gdp.K >> 5;
    for (int kt = 0; kt < nkt; ++kt) {
      __syncthreads();
      gload16(Ag, AsW);
      gload16(Bg, BsW);
      Ag += 32; Bg += 32;
      __syncthreads();
      b8 af[2], bfr[2];
#pragma unroll
      for (int i = 0; i < 2; ++i) af[i] = *(const b8*)&As[(wr + i * 16 + ln) * 32 + lq * 8];
#pragma unroll
      for (int j = 0; j < 2; ++j) bfr[j] = *(const b8*)&Bs[(wc + j * 16 + ln) * 32 + lq * 8];
#pragma unroll
      for (int i = 0; i < 2; ++i)
#pragma unroll
        for (int j = 0; j < 2; ++j)
          acc[i][j] = __builtin_amdgcn_mfma_f32_16x16x32_bf16(af[i], bfr[j], acc[i][j], 0, 0, 0);
    }
    u16* Cb = (u16*)gdp.C[0];
    u16* OT = gdp.OT[0];
    const u16* E0b = (const u16*)gdp.E0[0];
#pragma unroll
    for (int i = 0; i < 2; ++i) {
      const int mb = m0 + wr + i * 16 + lq * 4;
#pragma unroll
      for (int j = 0; j < 2; ++j) {
        const int n = n0 + wc + j * 16 + ln;
        if (n >= gdp.N) continue;
        u16 cq[4];
#pragma unroll
        for (int r = 0; r < 4; ++r) {
          const int m = mb + r;
          const u16 ub = f2b((acc[i][j][r] - b2f(E0b[(size_t)m * gdp.lde0 + n])) * gdp.p0);
          Cb[(size_t)m * gdp.ldc + n] = ub;
          cq[r] = ub;
        }
        *(uint2*)&OT[(size_t)n * gdp.ldt + mb] = pk4(cq[0], cq[1], cq[2], cq[3]);
      }
    }
  }
}

// ---------------- fused pair: T = W@A (y<16) || MT' = nsa*MT + MT@W (y>=16) ----------------
__global__ __launch_bounds__(256, 2) void fused_mt(GA gt, GA gm) {
  __shared__ u16 As[64 * 32];
  __shared__ u16 Bs[64 * 32];
  const int bz = blockIdx.z;
  const int mp = ((int)blockIdx.y >= 16) ? 1 : 0;
  const GA& g = mp ? gm : gt;
  const int m0 = ((int)blockIdx.y - (mp ? 16 : 0)) * 64, n0 = blockIdx.x * 64;
  const u16* __restrict__ A = g.A[bz];
  const u16* __restrict__ B = g.B[bz];
  const int lda = g.lda[bz], ldb = g.ldb[bz];
  const int tid = threadIdx.x, w = tid >> 6, lane = tid & 63;
  const int wr = (w >> 1) * 32, wc = (w & 1) * 32;
  const int ln = lane & 15, lq = lane >> 4;

  f32x4 acc[2][2];
#pragma unroll
  for (int i = 0; i < 2; ++i)
#pragma unroll
    for (int j = 0; j < 2; ++j)
#pragma unroll
      for (int r = 0; r < 4; ++r) acc[i][j][r] = 0.f;

  const u16* Ag = A + (size_t)(m0 + 16 * w + (lane >> 2)) * lda + (lane & 3) * 8;
  const u16* Bg = B + (size_t)(n0 + 16 * w + (lane >> 2)) * ldb + (lane & 3) * 8;
  u16* AsW = &As[w * 512];
  u16* BsW = &Bs[w * 512];
  const int nkt = g.K >> 5;

  for (int kt = 0; kt < nkt; ++kt) {
    __syncthreads();
    gload16(Ag, AsW);
    gload16(Bg, BsW);
    Ag += 32; Bg += 32;
    __syncthreads();
    b8 af[2], bfr[2];
#pragma unroll
    for (int i = 0; i < 2; ++i) af[i] = *(const b8*)&As[(wr + i * 16 + ln) * 32 + lq * 8];
#pragma unroll
    for (int j = 0; j < 2; ++j) bfr[j] = *(const b8*)&Bs[(wc + j * 16 + ln) * 32 + lq * 8];
#pragma unroll
    for (int i = 0; i < 2; ++i)
#pragma unroll
      for (int j = 0; j < 2; ++j)
        acc[i][j] = __builtin_amdgcn_mfma_f32_16x16x32_bf16(af[i], bfr[j], acc[i][j], 0, 0, 0);
  }

  u16* Cb = (u16*)g.C[bz];
  const u16* E0b = (const u16*)g.E0[bz];
#pragma unroll
  for (int i = 0; i < 2; ++i) {
    const int mb = m0 + wr + i * 16 + lq * 4;
#pragma unroll
    for (int j = 0; j < 2; ++j) {
      const int n = n0 + wc + j * 16 + ln;
      if (mp) {
#pragma unroll
        for (int r = 0; r < 4; ++r) {
          const int m = mb + r;
          Cb[(size_t)m * g.ldc + n] = f2b(g.p0 * b2f(E0b[(size_t)m * g.lde0 + n]) + acc[i][j][r]);
        }
      } else {
#pragma unroll
        for (int r = 0; r < 4; ++r) Cb[(size_t)(mb + r) * g.ldc + n] = f2b(acc[i][j][r]);
      }
    }
  }
}

// ---------------- fused pair: final gv<1> (y<ysplit) || PWt gemm_bt<0> (y>=ysplit) ----------------
__global__ __launch_bounds__(256, 2) void fused_pg(GA gp, GA ggv, int ysplit) {
  __shared__ u16 As[128 * 32];
  __shared__ u16 Bs[128 * 32];
  __shared__ u16 Vs[128 * 32];
  const int tid = threadIdx.x, w = tid >> 6, lane = tid & 63;
  const int wr = (w >> 1) * 64, wc = (w & 1) * 64;
  const int ln = lane & 15, lq = lane >> 4;

  if ((int)blockIdx.y < ysplit) {
    const u16* __restrict__ A = ggv.A[0];
    const u16* __restrict__ G = ggv.B[0];
    const u16* __restrict__ V = ggv.B[1];
    const int lda = ggv.lda[0], ldb = ggv.ldb[0];
    const int m0 = blockIdx.y * 128, n0 = blockIdx.x * 128;
    f32x4 ag[4][4], av[4][4];
#pragma unroll
    for (int i = 0; i < 4; ++i)
#pragma unroll
      for (int j = 0; j < 4; ++j)
#pragma unroll
        for (int r = 0; r < 4; ++r) { ag[i][j][r] = 0.f; av[i][j][r] = 0.f; }
    const u16* Agp = A + (size_t)(m0 + 32 * w + (lane >> 2)) * lda + (lane & 3) * 8;
    const u16* Ggp = G + (size_t)(n0 + 32 * w + (lane >> 2)) * ldb + (lane & 3) * 8;
    const u16* Vgp = V + (size_t)(n0 + 32 * w + (lane >> 2)) * ldb + (lane & 3) * 8;
    u16* AsW = &As[w * 1024];
    u16* GsW = &Bs[w * 1024];
    u16* VsW = &Vs[w * 1024];
    const int nkt = ggv.K >> 5;
    for (int kt = 0; kt < nkt; ++kt) {
      __syncthreads();
      gload16(Agp, AsW);
      gload16(Agp + (size_t)16 * lda, AsW + 512);
      gload16(Ggp, GsW);
      gload16(Ggp + (size_t)16 * ldb, GsW + 512);
      gload16(Vgp, VsW);
      gload16(Vgp + (size_t)16 * ldb, VsW + 512);
      Agp += 32; Ggp += 32; Vgp += 32;
      __syncthreads();
      b8 af[4], gf[4], vf[4];
#pragma unroll
      for (int i = 0; i < 4; ++i) af[i] = *(const b8*)&As[(wr + i * 16 + ln) * 32 + lq * 8];
#pragma unroll
      for (int j = 0; j < 4; ++j) gf[j] = *(const b8*)&Bs[(wc + j * 16 + ln) * 32 + lq * 8];
#pragma unroll
      for (int j = 0; j < 4; ++j) vf[j] = *(const b8*)&Vs[(wc + j * 16 + ln) * 32 + lq * 8];
#pragma unroll
      for (int i = 0; i < 4; ++i)
#pragma unroll
        for (int j = 0; j < 4; ++j) {
          ag[i][j] = __builtin_amdgcn_mfma_f32_16x16x32_bf16(af[i], gf[j], ag[i][j], 0, 0, 0);
          av[i][j] = __builtin_amdgcn_mfma_f32_16x16x32_bf16(af[i], vf[j], av[i][j], 0, 0, 0);
        }
    }
    u16* Hh = (u16*)ggv.C[0];
#pragma unroll
    for (int i = 0; i < 4; ++i) {
      const int mb = m0 + wr + i * 16 + lq * 4;
      if (mb >= ggv.M) continue;
#pragma unroll
      for (int j = 0; j < 4; ++j) {
        const int n = n0 + wc + j * 16 + ln;
#pragma unroll
        for (int r = 0; r < 4; ++r) {
          const float zg = ag[i][j][r];
          const float zv = av[i][j][r];
          const float s = 1.f / (1.f + __expf(-zg));
          Hh[(size_t)(mb + r) * ggv.ldc + n] = f2b(zg * s * zv);
        }
      }
    }
  } else {
    const int m0 = ((int)blockIdx.y - ysplit) * 128, n0 = blockIdx.x * 128;
    const u16* __restrict__ A = gp.A[0];
    const u16* __restrict__ B = gp.B[0];
    const int lda = gp.lda[0], ldb = gp.ldb[0];
    f32x4 acc[4][4];
#pragma unroll
    for (int i = 0; i < 4; ++i)
#pragma unroll
      for (int j = 0; j < 4; ++j)
#pragma unroll
        for (int r = 0; r < 4; ++r) acc[i][j][r] = 0.f;
    const u16* Ag = A + (size_t)(m0 + 32 * w + (lane >> 2)) * lda + (lane & 3) * 8;
    const u16* Bg = B + (size_t)(n0 + 32 * w + (lane >> 2)) * ldb + (lane & 3) * 8;
    u16* AsW = &As[w * 1024];
    u16* BsW = &Bs[w * 1024];
    const int nkt = gp.K >> 5;
    for (int kt = 0; kt < nkt; ++kt) {
      __syncthreads();
      gload16(Ag, AsW);
      gload16(Ag + (size_t)16 * lda, AsW + 512);
      gload16(Bg, BsW);
      gload16(Bg + (size_t)16 * ldb, BsW + 512);
      Ag += 32; Bg += 32;
      __syncthreads();
      b8 af[4], bfr[4];
#pragma unroll
      for (int i = 0; i < 4; ++i) af[i] = *(const b8*)&As[(wr + i * 16 + ln) * 32 + lq * 8];
#pragma unroll
      for (int j = 0; j < 4; ++j) bfr[j] = *(const b8*)&Bs[(wc + j * 16 + ln) * 32 + lq * 8];
#pragma unroll
      for (int i = 0; i < 4; ++i)
#pragma unroll
        for (int j = 0; j < 4; ++j)
          acc[i][j] = __builtin_amdgcn_mfma_f32_16x16x32_bf16(af[i], bfr[j], acc[i][j], 0, 0, 0);
    }
    u16* Cb = (u16*)gp.C[0];
#pragma unroll
    for (int i = 0; i < 4; ++i) {
      const int mb = m0 + wr + i * 16 + lq * 4;
#pragma unroll
      for (int j = 0; j < 4; ++j) {
        const int n = n0 + wc + j * 16 + ln;
#pragma unroll
        for (int r = 0; r < 4; ++r) Cb[(size_t)(mb + r) * gp.ldc + n] = f2b(acc[i][j][r]);
      }
    }
  }
}

// ---------------- 64x64 tile GEMM ----------------
// EPI: 0 Cb=acc | 2 v=(acc-E0b)*p0 -> Cb + OT(T-pack)
//      10 sym: Cb=acc + mirror | 11 sym: Cb=p0*E0b+p1*acc + mirror
//      12 sym: Cb=p0*E0b + p1*(E1[m,n]+E1[n,m]) + acc + mirror
//      13 sym: W=p0*E0b+p1*acc + mirror, AND M0=W+nsa*I -> OT (+ mirror)
//      15 Cb=p0*E0b[n,m] + acc
template <int EPI>
__global__ __launch_bounds__(256, 2) void gemm64(GA g) {
  if constexpr (EPI == 10 || EPI == 11 || EPI == 12 || EPI == 13) {
    if (blockIdx.x > blockIdx.y) return;
  }
  __shared__ u16 As[64 * 32];
  __shared__ u16 Bs[64 * 32];
  const int bz = blockIdx.z;
  const u16* __restrict__ A = g.A[bz];
  const u16* __restrict__ B = g.B[bz];
  const int lda = g.lda[bz], ldb = g.ldb[bz];
  const int m0 = blockIdx.y * 64, n0 = blockIdx.x * 64;
  const int tid = threadIdx.x, w = tid >> 6, lane = tid & 63;
  const int wr = (w >> 1) * 32, wc = (w & 1) * 32;
  const int ln = lane & 15, lq = lane >> 4;

  f32x4 acc[2][2];
#pragma unroll
  for (int i = 0; i < 2; ++i)
#pragma unroll
    for (int j = 0; j < 2; ++j)
#pragma unroll
      for (int r = 0; r < 4; ++r) acc[i][j][r] = 0.f;

  const u16* Ag = A + (size_t)(m0 + 16 * w + (lane >> 2)) * lda + (lane & 3) * 8;
  const u16* Bg = B + (size_t)(n0 + 16 * w + (lane >> 2)) * ldb + (lane & 3) * 8;
  u16* AsW = &As[w * 512];
  u16* BsW = &Bs[w * 512];
  const int nkt = g.K >> 5;

  for (int kt = 0; kt < nkt; ++kt) {
    __syncthreads();
    gload16(Ag, AsW);
    gload16(Bg, BsW);
    Ag += 32; Bg += 32;
    __syncthreads();
    b8 af[2], bfr[2];
#pragma unroll
    for (int i = 0; i < 2; ++i) af[i] = *(const b8*)&As[(wr + i * 16 + ln) * 32 + lq * 8];
#pragma unroll
    for (int j = 0; j < 2; ++j) bfr[j] = *(const b8*)&Bs[(wc + j * 16 + ln) * 32 + lq * 8];
#pragma unroll
    for (int i = 0; i < 2; ++i)
#pragma unroll
      for (int j = 0; j < 2; ++j)
        acc[i][j] = __builtin_amdgcn_mfma_f32_16x16x32_bf16(af[i], bfr[j], acc[i][j], 0, 0, 0);
  }

  u16* Cb = (u16*)g.C[bz];
  u16* OT = g.OT[bz];
  const u16* E0b = (const u16*)g.E0[bz];
  const u16* E1b = g.E1[bz];
  const bool offdiag = (blockIdx.x != blockIdx.y);

#pragma unroll
  for (int i = 0; i < 2; ++i) {
    const int mb = m0 + wr + i * 16 + lq * 4;
    if (mb >= g.M) continue;
#pragma unroll
    for (int j = 0; j < 2; ++j) {
      const int n = n0 + wc + j * 16 + ln;
      if (n >= g.N) continue;
      float vv[4];
#pragma unroll
      for (int r = 0; r < 4; ++r) vv[r] = acc[i][j][r];
      if constexpr (EPI == 0) {
#pragma unroll
        for (int r = 0; r < 4; ++r) Cb[(size_t)(mb + r) * g.ldc + n] = f2b(vv[r]);
      } else if constexpr (EPI == 2) {
        u16 cq[4];
#pragma unroll
        for (int r = 0; r < 4; ++r) {
          const int m = mb + r;
          const u16 ub = f2b((vv[r] - b2f(E0b[(size_t)m * g.lde0 + n])) * g.p0);
          Cb[(size_t)m * g.ldc + n] = ub;
          cq[r] = ub;
        }
        *(uint2*)&OT[(size_t)n * g.ldt + mb] = pk4(cq[0], cq[1], cq[2], cq[3]);
      } else if constexpr (EPI == 10) {
        u16 cq[4];
#pragma unroll
        for (int r = 0; r < 4; ++r) {
          cq[r] = f2b(vv[r]);
          Cb[(size_t)(mb + r) * g.ldc + n] = cq[r];
        }
        if (offdiag)
          *(uint2*)&Cb[(size_t)n * g.ldc + mb] = pk4(cq[0], cq[1], cq[2], cq[3]);
      } else if constexpr (EPI == 11) {
        u16 cq[4];
#pragma unroll
        for (int r = 0; r < 4; ++r) {
          cq[r] = f2b(g.p0 * b2f(E0b[(size_t)(mb + r) * g.lde0 + n]) + g.p1 * vv[r]);
          Cb[(size_t)(mb + r) * g.ldc + n] = cq[r];
        }
        if (offdiag)
          *(uint2*)&Cb[(size_t)n * g.ldc + mb] = pk4(cq[0], cq[1], cq[2], cq[3]);
      } else if constexpr (EPI == 12) {
        const uint2 t2u = *(const uint2*)&E1b[(size_t)n * g.lde1 + mb];
        const float t2v[4] = { b2f((u16)(t2u.x & 0xffff)), b2f((u16)(t2u.x >> 16)),
                               b2f((u16)(t2u.y & 0xffff)), b2f((u16)(t2u.y >> 16)) };
        u16 cq[4];
#pragma unroll
        for (int r = 0; r < 4; ++r) {
          const int m = mb + r;
          const float t1 = b2f(E1b[(size_t)m * g.lde1 + n]);
          const float a0 = b2f(E0b[(size_t)m * g.lde0 + n]);
          cq[r] = f2b(g.p0 * a0 + g.p1 * (t1 + t2v[r]) + vv[r]);
          Cb[(size_t)m * g.ldc + n] = cq[r];
        }
        if (offdiag)
          *(uint2*)&Cb[(size_t)n * g.ldc + mb] = pk4(cq[0], cq[1], cq[2], cq[3]);
      } else if constexpr (EPI == 13) {
        u16 cq[4], mq[4];
#pragma unroll
        for (int r = 0; r < 4; ++r) {
          const int m = mb + r;
          cq[r] = f2b(g.p0 * b2f(E0b[(size_t)m * g.lde0 + n]) + g.p1 * vv[r]);
          Cb[(size_t)m * g.ldc + n] = cq[r];
          float wv = b2f(cq[r]);
          if (m == n) wv += 3.4445f;
          mq[r] = f2b(wv);
          OT[(size_t)m * 1024 + n] = mq[r];
        }
        if (offdiag) {
          *(uint2*)&Cb[(size_t)n * g.ldc + mb] = pk4(cq[0], cq[1], cq[2], cq[3]);
          *(uint2*)&OT[(size_t)n * 1024 + mb] = pk4(mq[0], mq[1], mq[2], mq[3]);
        }
      } else if constexpr (EPI == 15) {
        const uint2 eu = *(const uint2*)&E0b[(size_t)n * g.lde0 + mb];
        const float e4[4] = { b2f((u16)(eu.x & 0xffff)), b2f((u16)(eu.x >> 16)),
                              b2f((u16)(eu.y & 0xffff)), b2f((u16)(eu.y >> 16)) };
#pragma unroll
        for (int r = 0; r < 4; ++r)
          Cb[(size_t)(mb + r) * g.ldc + n] = f2b(g.p0 * e4[r] + vv[r]);
      }
    }
  }
}

__global__ __launch_bounds__(256) void tr_f32b(const float* __restrict__ in, u16* __restrict__ out,
                                               int Cin, int Rtot) {
  __shared__ u16 t[32][33];
  const int c0 = blockIdx.x * 32, r0 = blockIdx.y * 32;
  const int tx = threadIdx.x, ty = threadIdx.y;
#pragma unroll
  for (int yy = 0; yy < 4; ++yy) {
    const int rr = ty * 4 + yy;
    t[rr][tx] = f2b(in[(size_t)(r0 + rr) * Cin + c0 + tx]);
  }
  __syncthreads();
#pragma unroll
  for (int yy = 0; yy < 4; ++yy) {
    const int cc = ty * 4 + yy;
    out[(size_t)(c0 + cc) * Rtot + r0 + tx] = t[tx][cc];
  }
}

__global__ void cvt_k(const float* __restrict__ in, u16* __restrict__ out, int n) {
  const int i = blockIdx.x * 256 + threadIdx.x;
  if (i < n) out[i] = f2b(in[i]);
}

__global__ void diag_k(float* __restrict__ out, int n, float val) {
  const int i = blockIdx.x * 256 + threadIdx.x;
  if (i < n) out[i] = val;
}

// zero token-tail cols [NTOK, NTOKA) of kT / vT
__global__ void zero_tail(u16* a, u16* b) {
  u16* p = (blockIdx.y ? b : a) + (size_t)blockIdx.x * NTOKA + NTOK;
  p[threadIdx.x & 255] = 0;
  if (threadIdx.x < 16) p[256 + threadIdx.x] = 0;
}

__global__ __launch_bounds__(256) void sumsq_k(const float* __restrict__ g, float* __restrict__ out) {
  const int b = blockIdx.y;
  const float* p = g + (size_t)b * PMi;
  float s = 0.f;
  for (int i = blockIdx.x * 256 + threadIdx.x; i < PMi; i += gridDim.x * 256) {
    float v = p[i]; s += v * v;
  }
  for (int off = 32; off > 0; off >>= 1) s += __shfl_xor(s, off);
  __shared__ float red[4];
  if ((threadIdx.x & 63) == 0) red[threadIdx.x >> 6] = s;
  __syncthreads();
  if (threadIdx.x == 0) atomicAdd(out + b, red[0] + red[1] + red[2] + red[3]);
}

__global__ __launch_bounds__(256) void scale_tr(const float* __restrict__ g, const float* __restrict__ ss,
                                                u16* __restrict__ Xb, u16* __restrict__ XbT) {
  const int b = blockIdx.z;
  __shared__ u16 t[32][33];
  const float r = 1.f / (sqrtf(ss[b]) + 1e-7f);
  const float* G = g + (size_t)b * PMi;
  u16* X = Xb + (size_t)b * PMi;
  u16* XT = XbT + (size_t)b * PMi;
  const int j0 = blockIdx.x * 32, i0 = blockIdx.y * 32;
  const int tx = threadIdx.x, ty = threadIdx.y;
#pragma unroll
  for (int yy = 0; yy < 4; ++yy) {
    const int rr = ty * 4 + yy;
    const u16 v = f2b(G[(size_t)(i0 + rr) * 4096 + j0 + tx] * r);
    X[(size_t)(i0 + rr) * 4096 + j0 + tx] = v;
    t[rr][tx] = v;
  }
  __syncthreads();
#pragma unroll
  for (int yy = 0; yy < 4; ++yy) {
    const int cc = ty * 4 + yy;
    XT[(size_t)(j0 + cc) * 1024 + i0 + tx] = t[tx][cc];
  }
}

static GA mk(const u16* A, const u16* B, void* C, int M, int N, int K,
             int lda, int ldb, int ldc) {
  GA a{};
  a.A[0] = a.A[1] = a.A[2] = A;
  a.B[0] = a.B[1] = a.B[2] = B;
  a.C[0] = a.C[1] = a.C[2] = C;
  a.lda[0] = a.lda[1] = a.lda[2] = lda;
  a.ldb[0] = a.ldb[1] = a.ldb[2] = ldb;
  a.M = M; a.N = N; a.K = K; a.ldc = ldc;
  return a;
}

extern "C" void kernel_launch(void* const* d_in, const int* in_sizes, int n_in,
                              void* d_out, int out_size, void* d_ws, size_t ws_size,
                              hipStream_t stream) {
  (void)in_sizes; (void)n_in;
  const float* x      = (const float*)d_in[0];
  const float* qkv_w  = (const float*)d_in[1];
  const float* qkv_b  = (const float*)d_in[2];
  const float* qn_s   = (const float*)d_in[3];
  const float* qn_b   = (const float*)d_in[4];
  const float* kn_s   = (const float*)d_in[5];
  const float* kn_b   = (const float*)d_in[6];
  const float* g_gate = (const float*)d_in[7];
  const float* g_val  = (const float*)d_in[8];
  const float* g_proj = (const float*)d_in[9];
  const float* proj_w = (const float*)d_in[10];
  const float* proj_b = (const float*)d_in[11];
  float* out = (float*)d_out;

  const size_t PM = PMi;
  const size_t TD = (size_t)NTOKA * 1024;
  const size_t PERS = 127926528ull;

  auto needD = [&](int chk) {
    return PERS + 9ull * (size_t)chk * 8192 + 4ull * (size_t)chk * 2048 + 50331648ull + 8192;
  };
  auto needP = [&](int chk) {
    return PERS + 7ull * (size_t)chk * 8192 + 2ull * (size_t)chk * 2048 + 50331648ull + 8192;
  };
  auto needU = [&](int chk) {
    return PERS + 5ull * (size_t)chk * 8192 + 2ull * (size_t)chk * 2048 + 50331648ull + 4096;
  };
  int CHKr, MODE;
  if      (ws_size >= needD(5632)) { CHKr = 5632; MODE = 2; }
  else if (ws_size >= needD(4096)) { CHKr = 4096; MODE = 2; }
  else if (ws_size >= needP(5632)) { CHKr = 5632; MODE = 1; }
  else if (ws_size >= needU(5632)) { CHKr = 5632; MODE = 0; }
  else if (ws_size >= needP(2816)) { CHKr = 2816; MODE = 1; }
  else if (ws_size >= needP(2048)) { CHKr = 2048; MODE = 1; }
  else if (ws_size >= needU(1408)) { CHKr = 1408; MODE = 0; }
  else {
    diag_k<<<dim3((out_size + 255) / 256), dim3(256), 0, stream>>>(out, out_size,
                                                                   (float)(ws_size >> 20));
    return;
  }

  char* p = (char*)d_ws;
  auto carve = [&](size_t bytes) { char* r = p; p += (bytes + 255) & ~(size_t)255; return (void*)r; };
  auto cdiv = [](int a, int b) { return (a + b - 1) / b; };
  auto mini = [](int a, int b) { return a < b ? a : b; };

  // ---- persistent (127.93 MB) ----
  u16* Gt     = (u16*)carve(PM * 2);
  u16* Vt     = (u16*)carve(PM * 2);
  u16* Pt     = (u16*)carve(PM * 2);
  u16* Pb     = (u16*)carve(PM * 2);
  u16* projWt = (u16*)carve(1048576ull * 2);
  u16* qb     = (u16*)carve(TD * 2);
  u16* kb     = (u16*)carve(TD * 2);
  u16* vT     = (u16*)carve(TD * 2);
  u16* kT     = (u16*)carve(TD * 2);
  float* ssq  = (float*)carve(256);
  char* arena = p;

  // P0 staging
  u16* xb    = (u16*)arena;
  u16* qkvWt = (u16*)(arena + 23068672);
  // P1 backward per chunk
  const size_t CB = (size_t)CHKr * 4096 * 2;
  const size_t DP = (size_t)CHKr * 1024 * 2;
  u16 *f1A[2], *f2A[2], *hhA[2], *hTA[2], *dpTA[2], *dpBA[2], *dzvT;
  float* gAll;
  if (MODE == 2) {
    f1A[0] = (u16*)(arena + 0 * CB);  f2A[0] = (u16*)(arena + 1 * CB);
    hhA[0] = (u16*)(arena + 2 * CB);  hTA[0] = (u16*)(arena + 3 * CB);
    f1A[1] = (u16*)(arena + 4 * CB);  f2A[1] = (u16*)(arena + 5 * CB);
    hhA[1] = (u16*)(arena + 6 * CB);  hTA[1] = (u16*)(arena + 7 * CB);
    dzvT   = (u16*)(arena + 8 * CB);
    dpTA[0] = (u16*)(arena + 9 * CB);          dpBA[0] = (u16*)(arena + 9 * CB + DP);
    dpTA[1] = (u16*)(arena + 9 * CB + 2 * DP); dpBA[1] = (u16*)(arena + 9 * CB + 3 * DP);
    gAll = (float*)(arena + 9 * CB + 4 * DP);
  } else {
    f1A[0] = f1A[1] = (u16*)arena;
    f2A[0] = f2A[1] = (u16*)(arena + CB);
    hhA[0] = (u16*)(arena + 2 * CB);
    hTA[0] = (u16*)(arena + 3 * CB);
    dzvT   = (u16*)(arena + 4 * CB);
    dpTA[0] = dpTA[1] = (u16*)(arena + 5 * CB);
    dpBA[0] = dpBA[1] = (u16*)(arena + 5 * CB + DP);
    gAll = (float*)(arena + 5 * CB + 2 * DP);
    hhA[1] = (MODE == 1) ? (u16*)(arena + 5 * CB + 2 * DP + 3 * PM * 4) : hhA[0];
    hTA[1] = (MODE == 1) ? (u16*)(arena + 6 * CB + 2 * DP + 3 * PM * 4) : hTA[0];
  }
  // P2 Newton-Schulz
  u16* XAb  = (u16*)arena;
  u16* XAbT = (u16*)(arena + 25165824);
  u16* Ab   = (u16*)(arena + 50331648);
  u16* Wb   = (u16*)(arena + 56623104);
  u16* Tb   = (u16*)(arena + 62914560);
  u16* Mb0  = (u16*)(arena + 69206016);
  u16* Mb1  = (u16*)(arena + 75497472);
  // P4 final forward
  u16* hbuf = (u16*)arena;
  u16* PWt  = (u16*)(arena + 92274688);

  const dim3 blk(256), tb32(32, 8);
  const float inv2 = 2.0f / (10992.0f * 1024.0f);
  const float nsa = 3.4445f, nsb = -4.7750f, nsc = 2.0315f;

  // ---- setup (round-6 structure; zero_tail instead of full kT/vT memsets) ----
  zero_tail<<<dim3(1024, 2), blk, 0, stream>>>(kT, vT);
  cvt_k<<<dim3(43968), blk, 0, stream>>>(x, xb, NTOK * 1024);
  cvt_k<<<dim3(16384), blk, 0, stream>>>(g_proj, Pb, (int)PM);
  tr_f32b<<<dim3(96, 32), tb32, 0, stream>>>(qkv_w, qkvWt, 3072, 1024);
  tr_f32b<<<dim3(32, 32), tb32, 0, stream>>>(proj_w, projWt, 1024, 1024);
  tr_f32b<<<dim3(128, 32), tb32, 0, stream>>>(g_gate, Gt, 4096, 1024);
  tr_f32b<<<dim3(128, 32), tb32, 0, stream>>>(g_val, Vt, 4096, 1024);
  tr_f32b<<<dim3(32, 128), tb32, 0, stream>>>(g_proj, Pt, 1024, 4096);

  {  // fused qkv + norm: writes qb, kb+kT, vT
    GA a = mk(xb, qkvWt, qb, NTOK, 3072, 1024, 1024, 1024, 1024);
    a.O1[0] = kb; a.OT[0] = kT; a.OT[1] = vT;
    a.E0[0] = qkv_b; a.E0[1] = qn_s; a.E0[2] = kn_s;
    a.E1[0] = (const u16*)qn_b; a.E1[1] = (const u16*)kn_b;
    gemm_qkv<<<dim3(24, 86, 1), blk, 0, stream>>>(a);
  }

  // ---- 2 TTT steps ----
  for (int step = 0; step < 2; ++step) {
    hipMemsetAsync(gAll, 0, 3 * PM * 4, stream);
    if (MODE == 2) {
      const int NC = cdiv(NTOK, CHKr);
      int c0P = 0, vcP = 0, mtP = 0;
      for (int ci = 0; ci < NC; ++ci) {
        const int c0 = ci * CHKr;
        const int vc = (NTOK - c0 < CHKr) ? (NTOK - c0) : CHKr;
        const int mt = cdiv(vc, 128);
        const int par = ci & 1, parP = par ^ 1;
        const int tail = (ci == NC - 1 && vc < CHKr);
        if (tail) hipMemsetAsync(hTA[par], 0, CB, stream);
        // GV(ci) || DH(ci-1)
        GA agv{};
        agv.A[0] = kb + (size_t)c0 * 1024; agv.lda[0] = 1024;
        agv.B[0] = Gt; agv.B[1] = Vt; agv.ldb[0] = 1024;
        agv.C[0] = f1A[par]; agv.O1[0] = f2A[par]; agv.O1[1] = hhA[par]; agv.OT[0] = hTA[par];
        agv.M = vc; agv.N = 4096; agv.K = 1024; agv.ldc = 4096; agv.ldt = CHKr;
        if (ci == 0) {
          gemm_gv<0><<<dim3(32, mt, 1), blk, 0, stream>>>(agv);
        } else {
          GA adh{};
          adh.A[0] = dpBA[parP]; adh.B[0] = Pb; adh.lda[0] = 1024; adh.ldb[0] = 1024;
          adh.C[0] = hhA[parP]; adh.O1[0] = dzvT;
          adh.E0[0] = f1A[parP]; adh.E1[0] = f2A[parP];
          adh.M = vcP; adh.N = 4096; adh.K = 1024; adh.ldt = CHKr;
          adh.lde0 = 4096; adh.lde1 = 4096;
          fused_hg<<<dim3(32, mt + mtP, 1), blk, 0, stream>>>(adh, agv, mt);
        }
        // DPRED(ci) || GRADS(ci-1) (split-K=2, atomic)
        if (tail) hipMemsetAsync(dpTA[par], 0, DP, stream);
        GA adp = mk(Pt, hhA[par], dpTA[par], 1024, vc, 4096, 4096, 4096, CHKr);
        adp.OT[0] = dpBA[par]; adp.ldt = 1024;
        adp.E0[0] = vT + c0; adp.lde0 = NTOKA; adp.p0 = inv2;
        const int dpx = cdiv(vc, 64);
        if (ci == 0) {
          gemm64<2><<<dim3(dpx, 16, 1), blk, 0, stream>>>(adp);
        } else {
          GA agr{};
          agr.A[0] = kT + c0P; agr.A[1] = kT + c0P; agr.A[2] = dpTA[parP];
          agr.lda[0] = NTOKA; agr.lda[1] = NTOKA; agr.lda[2] = CHKr;
          agr.B[0] = hhA[parP]; agr.B[1] = dzvT; agr.B[2] = hTA[parP];
          agr.ldb[0] = agr.ldb[1] = agr.ldb[2] = CHKr;
          agr.C[0] = gAll; agr.C[1] = gAll + PM; agr.C[2] = gAll + 2 * PM;
          agr.M = 1024; agr.N = 4096; agr.K = CHKr; agr.ldc = 4096;
          fused_gd<<<dim3(1536 + dpx * 16, 1, 1), blk, 0, stream>>>(agr, adp, 1536, dpx);
        }
        c0P = c0; vcP = vc; mtP = mt;
      }
      // epilogue: DH(last), GRADS(last; K clamped to kT bounds)
      const int par = (NC - 1) & 1;
      if (vcP < CHKr) {
        hipMemsetAsync(hhA[par], 0, CB, stream);
        hipMemsetAsync(dzvT, 0, CB, stream);
      }
      {
        GA adh = mk(dpBA[par], Pb, hhA[par], vcP, 4096, 1024, 1024, 1024, 0);
        adh.O1[0] = dzvT; adh.ldt = CHKr;
        adh.E0[0] = f1A[par]; adh.lde0 = 4096; adh.E1[0] = f2A[par]; adh.lde1 = 4096;
        gemm_bt<5, 0><<<dim3(32, mtP, 1), blk, 0, stream>>>(adh);
      }
      {
        GA agr{};
        agr.A[0] = kT + c0P; agr.A[1] = kT + c0P; agr.A[2] = dpTA[par];
        agr.lda[0] = NTOKA; agr.lda[1] = NTOKA; agr.lda[2] = CHKr;
        agr.B[0] = hhA[par]; agr.B[1] = dzvT; agr.B[2] = hTA[par];
        agr.ldb[0] = agr.ldb[1] = agr.ldb[2] = CHKr;
        agr.C[0] = gAll; agr.C[1] = gAll + PM; agr.C[2] = gAll + 2 * PM;
        agr.M = 1024; agr.N = 4096; agr.K = mini(CHKr, NTOKA - c0P); agr.ldc = 4096;
        gemm_bt<8, 1><<<dim3(32, 8, 6), blk, 0, stream>>>(agr);
      }
    } else {
      // MODE <= 1 fallback loop
      int havePend = 0;
      GA pendGA{};
      for (int ci = 0, c0 = 0; c0 < NTOK; ++ci, c0 += CHKr) {
        const int vc = (NTOK - c0 < CHKr) ? (NTOK - c0) : CHKr;
        const int mt = cdiv(vc, 128);
        const u16* kc = kb + (size_t)c0 * 1024;
        u16* hhp = hhA[ci & 1];
        u16* hTp = hTA[ci & 1];
        if (vc < CHKr) hipMemsetAsync(hTp, 0, CB, stream);
        {
          GA agv{};
          agv.A[0] = kc; agv.lda[0] = 1024;
          agv.B[0] = Gt; agv.B[1] = Vt; agv.ldb[0] = 1024;
          agv.C[0] = f1A[0]; agv.O1[0] = f2A[0]; agv.O1[1] = hhp; agv.OT[0] = hTp;
          agv.M = vc; agv.N = 4096; agv.K = 1024; agv.ldc = 4096; agv.ldt = CHKr;
          if (MODE == 1 && havePend) {
            fused_gg<<<dim3(32, mt + 48, 1), blk, 0, stream>>>(pendGA, agv, mt);
            havePend = 0;
          } else {
            gemm_gv<0><<<dim3(32, mt, 1), blk, 0, stream>>>(agv);
          }
        }
        if (vc < CHKr) {
          hipMemsetAsync(dzvT, 0, CB, stream);
          hipMemsetAsync(dpTA[0], 0, DP, stream);
        }
        {
          GA a = mk(Pt, hhp, dpTA[0], 1024, vc, 4096, 4096, 4096, CHKr);
          a.OT[0] = dpBA[0]; a.ldt = 1024;
          a.E0[0] = vT + c0; a.lde0 = NTOKA; a.p0 = inv2;
          gemm64<2><<<dim3(cdiv(vc, 64), 16, 1), blk, 0, stream>>>(a);
        }
        if (vc < CHKr) hipMemsetAsync(hhp, 0, CB, stream);
        {
          GA a = mk(dpBA[0], Pb, hhp, vc, 4096, 1024, 1024, 1024, 0);
          a.O1[0] = dzvT; a.ldt = CHKr;
          a.E0[0] = f1A[0]; a.lde0 = 4096; a.E1[0] = f2A[0]; a.lde1 = 4096;
          gemm_bt<5, 0><<<dim3(32, mt, 1), blk, 0, stream>>>(a);
        }
        {
          GA a{};
          a.A[0] = kT + c0; a.A[1] = kT + c0; a.A[2] = dpTA[0];
          a.lda[0] = NTOKA; a.lda[1] = NTOKA; a.lda[2] = CHKr;
          a.B[0] = hhp; a.B[1] = dzvT; a.B[2] = hTp;
          a.ldb[0] = a.ldb[1] = a.ldb[2] = CHKr;
          a.C[0] = gAll; a.C[1] = gAll + PM; a.C[2] = gAll + 2 * PM;
          a.M = 1024; a.N = 4096; a.K = mini(CHKr, NTOKA - c0); a.ldc = 4096;
          const int last = (c0 + CHKr >= NTOK);
          if (MODE == 1 && !last) { pendGA = a; havePend = 1; }
          else gemm_bt<8, 1><<<dim3(32, 8, 6), blk, 0, stream>>>(a);
        }
      }
    }
    // X0 = g/||g||_F
    hipMemsetAsync(ssq, 0, 16, stream);
    sumsq_k<<<dim3(512, 3), blk, 0, stream>>>(gAll, ssq);
    scale_tr<<<dim3(128, 32, 3), tb32, 0, stream>>>(gAll, ssq, XAb, XAbT);

    // Newton-Schulz x5: Gram recursion + M^T product accumulation; apply fused (EPI 16)
    {  // A0 = X0@X0^T
      GA a{};
      for (int b = 0; b < 3; ++b) {
        a.A[b] = XAb + (size_t)b * PM; a.B[b] = XAb + (size_t)b * PM;
        a.C[b] = Ab + (size_t)b * 1048576;
        a.lda[b] = 4096; a.ldb[b] = 4096;
      }
      a.M = 1024; a.N = 1024; a.K = 4096; a.ldc = 1024;
      gemm64<10><<<dim3(16, 16, 3), blk, 0, stream>>>(a);
    }
    for (int it = 0; it < 5; ++it) {
      {  // W = nsb*A + nsc*A@A (sym); it0 also emits M0 = W + nsa*I (EPI13)
        GA a{};
        for (int b = 0; b < 3; ++b) {
          a.A[b] = Ab + (size_t)b * 1048576; a.B[b] = Ab + (size_t)b * 1048576;
          a.C[b] = Wb + (size_t)b * 1048576; a.E0[b] = Ab + (size_t)b * 1048576;
          a.OT[b] = Mb0 + (size_t)b * 1048576;
          a.lda[b] = 1024; a.ldb[b] = 1024;
        }
        a.M = 1024; a.N = 1024; a.K = 1024; a.ldc = 1024; a.lde0 = 1024;
        a.p0 = nsb; a.p1 = nsc;
        if (it == 0) gemm64<13><<<dim3(16, 16, 3), blk, 0, stream>>>(a);
        else gemm64<11><<<dim3(16, 16, 3), blk, 0, stream>>>(a);
      }
      if (it == 0) {
        {  // T = W@A
          GA a{};
          for (int b = 0; b < 3; ++b) {
            a.A[b] = Wb + (size_t)b * 1048576; a.B[b] = Ab + (size_t)b * 1048576;
            a.C[b] = Tb + (size_t)b * 1048576;
            a.lda[b] = 1024; a.ldb[b] = 1024;
          }
          a.M = 1024; a.N = 1024; a.K = 1024; a.ldc = 1024;
          gemm64<0><<<dim3(16, 16, 3), blk, 0, stream>>>(a);
        }
      } else if (it < 4) {
        u16* Mti = (it & 1) ? Mb0 : Mb1;
        u16* Mto = (it & 1) ? Mb1 : Mb0;
        GA gt{}, gm{};
        for (int b = 0; b < 3; ++b) {
          gt.A[b] = Wb + (size_t)b * 1048576; gt.B[b] = Ab + (size_t)b * 1048576;
          gt.C[b] = Tb + (size_t)b * 1048576;
          gt.lda[b] = 1024; gt.ldb[b] = 1024;
          gm.A[b] = Mti + (size_t)b * 1048576; gm.B[b] = Wb + (size_t)b * 1048576;
          gm.C[b] = Mto + (size_t)b * 1048576; gm.E0[b] = Mti + (size_t)b * 1048576;
          gm.lda[b] = 1024; gm.ldb[b] = 1024;
        }
        gt.M = gt.N = 1024; gt.K = 1024; gt.ldc = 1024;
        gm.M = gm.N = 1024; gm.K = 1024; gm.ldc = 1024; gm.lde0 = 1024; gm.p0 = nsa;
        fused_mt<<<dim3(16, 32, 3), blk, 0, stream>>>(gt, gm);
      } else {
        GA a{};
        for (int b = 0; b < 3; ++b) {
          a.A[b] = Wb + (size_t)b * 1048576; a.B[b] = Mb1 + (size_t)b * 1048576;
          a.C[b] = Mb0 + (size_t)b * 1048576; a.E0[b] = Mb1 + (size_t)b * 1048576;
          a.lda[b] = 1024; a.ldb[b] = 1024;
        }
        a.M = 1024; a.N = 1024; a.K = 1024; a.ldc = 1024; a.lde0 = 1024; a.p0 = nsa;
        gemm64<15><<<dim3(16, 16, 3), blk, 0, stream>>>(a);
      }
      if (it < 4) {  // A' = nsa^2*A + nsa*(T+T^T) + T@W
        GA a{};
        for (int b = 0; b < 3; ++b) {
          a.A[b] = Tb + (size_t)b * 1048576; a.B[b] = Wb + (size_t)b * 1048576;
          a.C[b] = Ab + (size_t)b * 1048576;
          a.E0[b] = Ab + (size_t)b * 1048576; a.E1[b] = Tb + (size_t)b * 1048576;
          a.lda[b] = 1024; a.ldb[b] = 1024;
        }
        a.M = 1024; a.N = 1024; a.K = 1024; a.ldc = 1024;
        a.lde0 = 1024; a.lde1 = 1024;
        a.p0 = nsa * nsa; a.p1 = nsa;
        gemm64<12><<<dim3(16, 16, 3), blk, 0, stream>>>(a);
      }
    }
    {  // fused apply: X5 = M4@X0; Muon RMW on Gt/Vt/Pb (+Pt scatter)
      GA a{};
      for (int b = 0; b < 3; ++b) {
        a.A[b] = Mb0 + (size_t)b * 1048576; a.B[b] = XAbT + (size_t)b * PM;
        a.lda[b] = 1024; a.ldb[b] = 1024;
      }
      a.C[0] = Gt; a.C[1] = Vt; a.C[2] = Pb;
      a.O1[0] = nullptr; a.O1[1] = nullptr; a.O1[2] = Pt;
      a.M = 1024; a.N = 4096; a.K = 1024; a.ldc = 1024;
      gemm_bt<16, 0><<<dim3(32, 8, 3), blk, 0, stream>>>(a);
    }
  }

  // ---- final: [h = swish(q@G)*q@V  ||  PWt = (P@projW)^T], then out = h@PWt + b ----
  {
    GA agv{};
    agv.A[0] = qb; agv.lda[0] = 1024;
    agv.B[0] = Gt; agv.B[1] = Vt; agv.ldb[0] = 1024;
    agv.C[0] = hbuf;
    agv.M = NTOK; agv.N = 4096; agv.K = 1024; agv.ldc = 4096;
    GA ap = mk(projWt, Pb, PWt, 1024, 4096, 1024, 1024, 1024, 4096);
    fused_pg<<<dim3(32, 94, 1), blk, 0, stream>>>(ap, agv, 86);
  }
  {
    GA a = mk(hbuf, PWt, out, NTOK, 1024, 4096, 4096, 4096, 1024);
    a.E0[0] = proj_b;
    gemm_bt<6, 0><<<dim3(8, 86, 1), blk, 0, stream>>>(a);
  }
}